// Round 6
// baseline (323.629 us; speedup 1.0000x reference)
//
#include <hip/hip_runtime.h>
#include <cstdint>

#define WDIM 128
#define NPX  16384           // 128*128
#define QSTR 136             // bf16 q/kT LDS row stride (shorts), 16B-aligned rows
// LDS layout (bytes): qb [0,34816) | kT [34816,69632) | red at 69632.
#define LDS_A_BYTES 69760

typedef __attribute__((ext_vector_type(8))) short short8;
typedef __attribute__((ext_vector_type(4))) float f32x4;

__device__ __forceinline__ float wave_max(float v) {
#pragma unroll
  for (int m = 32; m >= 1; m >>= 1) v = fmaxf(v, __shfl_xor(v, m));
  return v;
}
__device__ __forceinline__ float wave_sum(float v) {
#pragma unroll
  for (int m = 32; m >= 1; m >>= 1) v += __shfl_xor(v, m);
  return v;
}
__device__ __forceinline__ unsigned short f2bf(float f) {
  uint32_t u = __float_as_uint(f);
  return (unsigned short)((u + 0x7fff + ((u >> 16) & 1)) >> 16);
}
__device__ __forceinline__ float bf2f(unsigned short h) {
  return __uint_as_float(((uint32_t)h) << 16);
}
__device__ __forceinline__ float sgpr_f(float v) {
  return __uint_as_float(__builtin_amdgcn_readfirstlane(__float_as_uint(v)));
}

// load a 32-float window (cols c0h-8 .. c0h+24) of one global row.
// Edge 16B-blocks outside [0,128) are skipped (no OOB) and zeroed.
__device__ __forceinline__ void load_win_g(float* xw, const float* rowp,
                                           int c0h, bool mlo, bool mhi) {
  const float* bp = rowp + c0h - 8;
#pragma unroll
  for (int k = 0; k < 8; ++k) {
    if ((k < 2 && mlo) || (k >= 6 && mhi)) {
      xw[4 * k] = 0.f; xw[4 * k + 1] = 0.f; xw[4 * k + 2] = 0.f; xw[4 * k + 3] = 0.f;
    } else {
      *(float4*)&xw[4 * k] = *(const float4*)&bp[4 * k];
    }
  }
}

template <int OFF>
__device__ __forceinline__ void tap16(float* acc, const float* xw, float w) {
#pragma unroll
  for (int i = 0; i < 16; ++i) acc[i] = fmaf(w, xw[8 + OFF + i], acc[i]);
}

// ---------------- Kernel A: conv(global) -> bf16 MFMA -> softmax -> *pool ---
// grid 2048 (= B*C), block 512 (8 waves). thread -> row r=t>>2, cols cb*32..+31
__global__ __launch_bounds__(512, 4)
void kA(const float* __restrict__ x, const float* __restrict__ wq,
        const float* __restrict__ bq, const float* __restrict__ wk,
        const float* __restrict__ bk, unsigned short* __restrict__ y) {
  extern __shared__ char smem[];
  unsigned short* qb = (unsigned short*)smem;            // q bf16 [128][QSTR]
  unsigned short* kt = (unsigned short*)(smem + 34816);  // kT bf16 [128][QSTR]
  float* red = (float*)(smem + 69632);

  const int bc = blockIdx.x;
  const int t = threadIdx.x;
  const float* __restrict__ xp = x + (size_t)bc * NPX;

  const int ch = bc & 255;
  float q9[9], k9[9];
#pragma unroll
  for (int i = 0; i < 9; ++i) {
    q9[i] = sgpr_f(wq[ch * 9 + i]);
    k9[i] = sgpr_f(wk[ch * 9 + i]);
  }
  const float bqv = sgpr_f(bq[ch]), bkv = sgpr_f(bk[ch]);

  const int r = t >> 2, cb = t & 3;

  // masked weights for out-of-plane rows (value rows are clamped; w=0 kills them)
  float ktm[3], qtm[3], qbm[3], kbm[3];
#pragma unroll
  for (int i = 0; i < 3; ++i) {
    ktm[i] = (r >= 6)  ? k9[i]     : 0.f;
    qtm[i] = (r >= 3)  ? q9[i]     : 0.f;
    qbm[i] = (r < 125) ? q9[6 + i] : 0.f;
    kbm[i] = (r < 122) ? k9[6 + i] : 0.f;
  }
  const float* rm6 = xp + (r >= 6 ? r - 6 : 0) * WDIM;
  const float* rm3 = xp + (r >= 3 ? r - 3 : 0) * WDIM;
  const float* r00 = xp + r * WDIM;
  const float* rp3 = xp + (r < 125 ? r + 3 : 127) * WDIM;
  const float* rp6 = xp + (r < 122 ? r + 6 : 127) * WDIM;

  float psum = 0.f;
#pragma unroll
  for (int h = 0; h < 2; ++h) {
    const int c0h = cb * 32 + h * 16;
    const bool mlo = (cb == 0) && (h == 0);
    const bool mhi = (cb == 3) && (h == 1);
    float aqh[16], akh[16];
#pragma unroll
    for (int i = 0; i < 16; ++i) { aqh[i] = bqv; akh[i] = bkv; }

    float xw[32];
    load_win_g(xw, rm6, c0h, mlo, mhi);
    tap16<-6>(akh, xw, ktm[0]); tap16<0>(akh, xw, ktm[1]); tap16<6>(akh, xw, ktm[2]);
    load_win_g(xw, rm3, c0h, mlo, mhi);
    tap16<-3>(aqh, xw, qtm[0]); tap16<0>(aqh, xw, qtm[1]); tap16<3>(aqh, xw, qtm[2]);
    load_win_g(xw, r00, c0h, mlo, mhi);
    tap16<-3>(aqh, xw, q9[3]); tap16<0>(aqh, xw, q9[4]); tap16<3>(aqh, xw, q9[5]);
    tap16<-6>(akh, xw, k9[3]); tap16<0>(akh, xw, k9[4]); tap16<6>(akh, xw, k9[5]);
    load_win_g(xw, rp3, c0h, mlo, mhi);
    tap16<-3>(aqh, xw, qbm[0]); tap16<0>(aqh, xw, qbm[1]); tap16<3>(aqh, xw, qbm[2]);
    load_win_g(xw, rp6, c0h, mlo, mhi);
    tap16<-6>(akh, xw, kbm[0]); tap16<0>(akh, xw, kbm[1]); tap16<6>(akh, xw, kbm[2]);

    // write this half: q row-major (vectorized) + kT (scalar b16)
#pragma unroll
    for (int g = 0; g < 2; ++g) {
      short8 pk;
#pragma unroll
      for (int j = 0; j < 8; ++j) pk[j] = (short)f2bf(aqh[g * 8 + j]);
      *(short8*)&qb[r * QSTR + c0h + g * 8] = pk;
    }
#pragma unroll
    for (int i = 0; i < 16; ++i) {
      kt[(c0h + i) * QSTR + r] = f2bf(akh[i]);
      psum += akh[i];
    }
  }
  __syncthreads();

  // MFMA: attn = q @ k. wave w: rows wr*64..+63, cols wc*32..+31
  const int w = t >> 6, lane = t & 63;
  const int wr = w >> 2, wc = w & 3;
  const int r16 = lane & 15, kg = lane >> 4;
  f32x4 acc[4][2];
#pragma unroll
  for (int mi = 0; mi < 4; ++mi)
#pragma unroll
    for (int ni = 0; ni < 2; ++ni) acc[mi][ni] = (f32x4){0.f, 0.f, 0.f, 0.f};

#pragma unroll
  for (int kk = 0; kk < 4; ++kk) {
    const int kb = kk * 32 + kg * 8;
    short8 a0 = *(const short8*)&qb[(wr * 64 + 0 * 16 + r16) * QSTR + kb];
    short8 a1 = *(const short8*)&qb[(wr * 64 + 1 * 16 + r16) * QSTR + kb];
    short8 a2 = *(const short8*)&qb[(wr * 64 + 2 * 16 + r16) * QSTR + kb];
    short8 a3 = *(const short8*)&qb[(wr * 64 + 3 * 16 + r16) * QSTR + kb];
    short8 b0 = *(const short8*)&kt[(wc * 32 + 0 + r16) * QSTR + kb];
    short8 b1 = *(const short8*)&kt[(wc * 32 + 16 + r16) * QSTR + kb];
    acc[0][0] = __builtin_amdgcn_mfma_f32_16x16x32_bf16(a0, b0, acc[0][0], 0, 0, 0);
    acc[0][1] = __builtin_amdgcn_mfma_f32_16x16x32_bf16(a0, b1, acc[0][1], 0, 0, 0);
    acc[1][0] = __builtin_amdgcn_mfma_f32_16x16x32_bf16(a1, b0, acc[1][0], 0, 0, 0);
    acc[1][1] = __builtin_amdgcn_mfma_f32_16x16x32_bf16(a1, b1, acc[1][1], 0, 0, 0);
    acc[2][0] = __builtin_amdgcn_mfma_f32_16x16x32_bf16(a2, b0, acc[2][0], 0, 0, 0);
    acc[2][1] = __builtin_amdgcn_mfma_f32_16x16x32_bf16(a2, b1, acc[2][1], 0, 0, 0);
    acc[3][0] = __builtin_amdgcn_mfma_f32_16x16x32_bf16(a3, b0, acc[3][0], 0, 0, 0);
    acc[3][1] = __builtin_amdgcn_mfma_f32_16x16x32_bf16(a3, b1, acc[3][1], 0, 0, 0);
  }

  // plane softmax + pool scale
  float amax = -3.402823466e38f;
#pragma unroll
  for (int mi = 0; mi < 4; ++mi)
#pragma unroll
    for (int ni = 0; ni < 2; ++ni)
#pragma unroll
      for (int j = 0; j < 4; ++j) amax = fmaxf(amax, acc[mi][ni][j]);
  amax = wave_max(amax);
  if (lane == 0) red[w] = amax;
  __syncthreads();
  float bmax = red[0];
#pragma unroll
  for (int w2 = 1; w2 < 8; ++w2) bmax = fmaxf(bmax, red[w2]);

  float es = 0.f;
#pragma unroll
  for (int mi = 0; mi < 4; ++mi)
#pragma unroll
    for (int ni = 0; ni < 2; ++ni)
#pragma unroll
      for (int j = 0; j < 4; ++j) {
        float e = __expf(acc[mi][ni][j] - bmax);
        acc[mi][ni][j] = e;
        es += e;
      }
  es = wave_sum(es);
  float ps = wave_sum(psum);
  if (lane == 0) { red[8 + w] = es; red[16 + w] = ps; }
  __syncthreads();
  float tsum = 0.f, tpool = 0.f;
#pragma unroll
  for (int w2 = 0; w2 < 8; ++w2) { tsum += red[8 + w2]; tpool += red[16 + w2]; }
  const float scale = (tpool * (1.f / 16384.f)) / tsum;

  unsigned short* __restrict__ yp = y + (size_t)bc * NPX;
#pragma unroll
  for (int mi = 0; mi < 4; ++mi)
#pragma unroll
    for (int ni = 0; ni < 2; ++ni) {
      const int col = wc * 32 + ni * 16 + r16;
#pragma unroll
      for (int j = 0; j < 4; ++j) {
        const int row = wr * 64 + mi * 16 + kg * 4 + j;
        yp[row * WDIM + col] = f2bf(acc[mi][ni][j] * scale);
      }
    }
}

// ---------------- Kernel S: s = w_sq . y via MFMA + stats + sT (bf16) -------
__global__ __launch_bounds__(256, 2)
void kS(const unsigned short* __restrict__ y, const float* __restrict__ w_sq,
        unsigned short* __restrict__ sT, float* __restrict__ partials) {
  __shared__ unsigned short yT[64][264];
  __shared__ float red[256];
  const int t = threadIdx.x;
  const int w = t >> 6, lane = t & 63;
  const int r16 = lane & 15, kg = lane >> 4;
  const int b = blockIdx.x >> 6;
  const int chunk = blockIdx.x & 63;
  const unsigned short* __restrict__ yb = y + (size_t)b * 256 * NPX;

  short8 aw[2][8];
#pragma unroll
  for (int mt = 0; mt < 2; ++mt)
#pragma unroll
    for (int ks = 0; ks < 8; ++ks) {
      const float* p = &w_sq[(mt * 16 + r16) * 256 + ks * 32 + kg * 8];
      float4 f0 = *(const float4*)p;
      float4 f1 = *(const float4*)(p + 4);
      short8 a;
      a[0] = f2bf(f0.x); a[1] = f2bf(f0.y); a[2] = f2bf(f0.z); a[3] = f2bf(f0.w);
      a[4] = f2bf(f1.x); a[5] = f2bf(f1.y); a[6] = f2bf(f1.z); a[7] = f2bf(f1.w);
      aw[mt][ks] = a;
    }

  float ssum[8], ssq[8];
#pragma unroll
  for (int i = 0; i < 8; ++i) { ssum[i] = 0.f; ssq[i] = 0.f; }

  for (int st = 0; st < 4; ++st) {
    const int p0 = chunk * 256 + st * 64;
#pragma unroll
    for (int it = 0; it < 8; ++it) {
      const int tid = it * 4 + w;
      const int cg = tid & 3, pg = tid >> 2;
      const int c = cg * 64 + lane;
      short8 v = *(const short8*)&yb[(size_t)c * NPX + p0 + pg * 8];
#pragma unroll
      for (int j = 0; j < 8; ++j) yT[pg * 8 + j][c] = (unsigned short)v[j];
    }
    __syncthreads();

    f32x4 acc[2][4];
#pragma unroll
    for (int mi = 0; mi < 2; ++mi)
#pragma unroll
      for (int ni = 0; ni < 4; ++ni) acc[mi][ni] = (f32x4){0.f, 0.f, 0.f, 0.f};

#pragma unroll
    for (int ks = 0; ks < 8; ++ks) {
#pragma unroll
      for (int ni = 0; ni < 4; ++ni) {
        short8 bv = *(const short8*)&yT[ni * 16 + r16][ks * 32 + kg * 8];
        acc[0][ni] = __builtin_amdgcn_mfma_f32_16x16x32_bf16(aw[0][ks], bv, acc[0][ni], 0, 0, 0);
        acc[1][ni] = __builtin_amdgcn_mfma_f32_16x16x32_bf16(aw[1][ks], bv, acc[1][ni], 0, 0, 0);
      }
    }

#pragma unroll
    for (int mi = 0; mi < 2; ++mi)
#pragma unroll
      for (int ni = 0; ni < 4; ++ni) {
        const int px = p0 + ni * 16 + r16;
        ushort4 pk;
#pragma unroll
        for (int j = 0; j < 4; ++j) {
          float v = acc[mi][ni][j];
          ssum[mi * 4 + j] += v;
          ssq[mi * 4 + j] += v * v;
          ((unsigned short*)&pk)[j] = f2bf(v);
        }
        *(ushort4*)&sT[((size_t)b * NPX + px) * 32 + mi * 16 + kg * 4] = pk;
      }
    __syncthreads();
  }

#pragma unroll
  for (int i = 0; i < 8; ++i) {
    float sm = ssum[i], sq = ssq[i];
#pragma unroll
    for (int m = 8; m >= 1; m >>= 1) {
      sm += __shfl_xor(sm, m);
      sq += __shfl_xor(sq, m);
    }
    if (r16 == 0) {
      const int d = (i >> 2) * 16 + kg * 4 + (i & 3);
      red[w * 64 + d] = sm;
      red[w * 64 + 32 + d] = sq;
    }
  }
  __syncthreads();
  if (t < 64) {
    float tot = red[t] + red[64 + t] + red[128 + t] + red[192 + t];
    partials[(size_t)blockIdx.x * 64 + t] = tot;
  }
}

// ---------------- Kernel R: partials -> mu, rs ------------------------------
__global__ void kR(const float* __restrict__ partials, float* __restrict__ mu_rs) {
  const int b = blockIdx.x, d = threadIdx.x;
  float sm = 0.f, sq = 0.f;
  for (int ch = 0; ch < 64; ++ch) {
    const float* pp = &partials[(size_t)(b * 64 + ch) * 64];
    sm += pp[d];
    sq += pp[32 + d];
  }
  float m = sm * (1.f / 16384.f);
  float v = sq * (1.f / 16384.f) - m * m;
  mu_rs[b * 64 + d] = m;
  mu_rs[b * 64 + 32 + d] = rsqrtf(v + 1e-5f);
}

// ---------------- Kernel O: out = w_ex . relu((s-mu)*rs) + b_ex (MFMA) ------
__global__ __launch_bounds__(256, 3)
void kO(const unsigned short* __restrict__ sT, const float* __restrict__ mu_rs,
        const float* __restrict__ w_ex, const float* __restrict__ b_ex,
        float* __restrict__ out) {
  const int t = threadIdx.x;
  const int w = t >> 6, lane = t & 63;
  const int r16 = lane & 15, kg = lane >> 4;
  const int b = blockIdx.x >> 8;
  const int p0 = (blockIdx.x & 255) * 64;
  const int c0 = w * 64;

  short8 aw[4];
#pragma unroll
  for (int mt = 0; mt < 4; ++mt) {
    const int c = c0 + mt * 16 + r16;
    const float* p = &w_ex[c * 32 + kg * 8];
    float4 f0 = *(const float4*)p;
    float4 f1 = *(const float4*)(p + 4);
    short8 a;
    a[0] = f2bf(f0.x); a[1] = f2bf(f0.y); a[2] = f2bf(f0.z); a[3] = f2bf(f0.w);
    a[4] = f2bf(f1.x); a[5] = f2bf(f1.y); a[6] = f2bf(f1.z); a[7] = f2bf(f1.w);
    aw[mt] = a;
  }

  float m8[8], r8[8];
  {
    const float* mp = &mu_rs[b * 64 + kg * 8];
    const float* rp = &mu_rs[b * 64 + 32 + kg * 8];
#pragma unroll
    for (int q = 0; q < 8; ++q) { m8[q] = mp[q]; r8[q] = rp[q]; }
  }

  f32x4 acc[4][4];
#pragma unroll
  for (int mt = 0; mt < 4; ++mt)
#pragma unroll
    for (int ni = 0; ni < 4; ++ni) acc[mt][ni] = (f32x4){0.f, 0.f, 0.f, 0.f};

#pragma unroll
  for (int ni = 0; ni < 4; ++ni) {
    const int px = p0 + ni * 16 + r16;
    short8 sv = *(const short8*)&sT[((size_t)b * NPX + px) * 32 + kg * 8];
    short8 hb;
#pragma unroll
    for (int q = 0; q < 8; ++q) {
      float f = bf2f((unsigned short)sv[q]);
      float h = fmaxf((f - m8[q]) * r8[q], 0.f);
      hb[q] = f2bf(h);
    }
#pragma unroll
    for (int mt = 0; mt < 4; ++mt)
      acc[mt][ni] = __builtin_amdgcn_mfma_f32_16x16x32_bf16(aw[mt], hb, acc[mt][ni], 0, 0, 0);
  }

  float* __restrict__ ob = out + (size_t)b * 256 * NPX;
#pragma unroll
  for (int mt = 0; mt < 4; ++mt) {
#pragma unroll
    for (int j = 0; j < 4; ++j) {
      const int c = c0 + mt * 16 + kg * 4 + j;
      const float bv = b_ex[c];
#pragma unroll
      for (int ni = 0; ni < 4; ++ni) {
        const int px = p0 + ni * 16 + r16;
        ob[(size_t)c * NPX + px] = acc[mt][ni][j] + bv;
      }
    }
  }
}

extern "C" void kernel_launch(void* const* d_in, const int* in_sizes, int n_in,
                              void* d_out, int out_size, void* d_ws, size_t ws_size,
                              hipStream_t stream) {
  (void)in_sizes; (void)n_in; (void)out_size; (void)ws_size;
  const float* x    = (const float*)d_in[0];
  const float* wq   = (const float*)d_in[1];
  const float* bq   = (const float*)d_in[2];
  const float* wk   = (const float*)d_in[3];
  const float* bk   = (const float*)d_in[4];
  const float* w_sq = (const float*)d_in[5];
  // d_in[6] = b_sq: unused — per-channel bias before InstanceNorm cancels
  const float* w_ex = (const float*)d_in[7];
  const float* b_ex = (const float*)d_in[8];
  float* out = (float*)d_out;

  unsigned short* sT = (unsigned short*)d_ws;
  float* partials = (float*)((char*)d_ws + (size_t)8 * NPX * 32 * 2);
  float* mu_rs = partials + (size_t)512 * 64;

  unsigned short* ybf = (unsigned short*)d_out;

  hipFuncSetAttribute((const void*)kA, hipFuncAttributeMaxDynamicSharedMemorySize,
                      LDS_A_BYTES);

  kA<<<2048, 512, LDS_A_BYTES, stream>>>(x, wq, bq, wk, bk, ybf);
  kS<<<512, 256, 0, stream>>>(ybf, w_sq, sT, partials);
  kR<<<8, 32, 0, stream>>>(partials, mu_rs);
  kO<<<2048, 256, 0, stream>>>(sT, mu_rs, w_ex, b_ex, out);
}

// Round 7
// 201.589 us; speedup vs baseline: 1.6054x; 1.6054x over previous
//
#include <hip/hip_runtime.h>
#include <cstdint>

#define WDIM 128
#define NPX  16384           // 128*128
#define QSTR 136             // bf16 q/kT LDS row stride (shorts), 16B-aligned rows
#define GUARD 8              // front guard (floats) for edge window reads
// x LDS layout: addr(r,c) = GUARD + 132*r + 33*(c>>5) + (c&31)  (fp32)
//   -> window-read bank = 4*(r%8) + cb + const (mod 32): uniform 2-way, free.
// x region ~67.7KB; after conv barrier overlaid by:
// qb [0,34816) | kT [34816,69632) | red at 69632. Total 69760 -> 2 blocks/CU.
#define LDS_A_BYTES 69760

typedef __attribute__((ext_vector_type(8))) short short8;
typedef __attribute__((ext_vector_type(4))) float f32x4;

__device__ __forceinline__ float wave_max(float v) {
#pragma unroll
  for (int m = 32; m >= 1; m >>= 1) v = fmaxf(v, __shfl_xor(v, m));
  return v;
}
__device__ __forceinline__ float wave_sum(float v) {
#pragma unroll
  for (int m = 32; m >= 1; m >>= 1) v += __shfl_xor(v, m);
  return v;
}
__device__ __forceinline__ unsigned short f2bf(float f) {
  uint32_t u = __float_as_uint(f);
  return (unsigned short)((u + 0x7fff + ((u >> 16) & 1)) >> 16);
}
__device__ __forceinline__ float bf2f(unsigned short h) {
  return __uint_as_float(((uint32_t)h) << 16);
}
__device__ __forceinline__ float sgpr_f(float v) {
  return __uint_as_float(__builtin_amdgcn_readfirstlane(__float_as_uint(v)));
}

// load one 28-float window (16 px + 6 halo each side) of a segmented row.
template <int H>
__device__ __forceinline__ void load_win28(float* xw, const float* rowp,
                                           bool mlo, bool mhi) {
#pragma unroll
  for (int w = 0; w < 28; ++w) {
    int off;
    if (H == 0) off = (w < 6) ? (w - 7) : (w - 6);
    else        off = (w < 22) ? (w + 10) : (w + 11);
    xw[w] = rowp[off];
  }
  if (H == 0 && mlo) {
#pragma unroll
    for (int w = 0; w < 6; ++w) xw[w] = 0.f;
  }
  if (H == 1 && mhi) {
#pragma unroll
    for (int w = 22; w < 28; ++w) xw[w] = 0.f;
  }
}

template <int OFF>
__device__ __forceinline__ void tap16h(float* acc, const float* xw, float w) {
#pragma unroll
  for (int i = 0; i < 16; ++i) acc[i] = fmaf(w, xw[6 + OFF + i], acc[i]);
}

template <int H>
__device__ __forceinline__ void conv_half(float* aqh, float* akh,
    const float* rm6, const float* rm3, const float* r00, const float* rp3,
    const float* rp6, const float* q9, const float* k9, const float* ktm,
    const float* qtm, const float* qbm, const float* kbm, bool mlo, bool mhi) {
  float xw[28];
  load_win28<H>(xw, rm6, mlo, mhi);
  tap16h<-6>(akh, xw, ktm[0]); tap16h<0>(akh, xw, ktm[1]); tap16h<6>(akh, xw, ktm[2]);
  load_win28<H>(xw, rm3, mlo, mhi);
  tap16h<-3>(aqh, xw, qtm[0]); tap16h<0>(aqh, xw, qtm[1]); tap16h<3>(aqh, xw, qtm[2]);
  load_win28<H>(xw, r00, mlo, mhi);
  tap16h<-3>(aqh, xw, q9[3]); tap16h<0>(aqh, xw, q9[4]); tap16h<3>(aqh, xw, q9[5]);
  tap16h<-6>(akh, xw, k9[3]); tap16h<0>(akh, xw, k9[4]); tap16h<6>(akh, xw, k9[5]);
  load_win28<H>(xw, rp3, mlo, mhi);
  tap16h<-3>(aqh, xw, qbm[0]); tap16h<0>(aqh, xw, qbm[1]); tap16h<3>(aqh, xw, qbm[2]);
  load_win28<H>(xw, rp6, mlo, mhi);
  tap16h<-6>(akh, xw, kbm[0]); tap16h<0>(akh, xw, kbm[1]); tap16h<6>(akh, xw, kbm[2]);
}

// ---------------- Kernel A: conv -> bf16 MFMA matmul -> softmax -> *pool ----
// grid 2048 (= B*C), block 512 (8 waves). thread -> row r=t>>2, cols cb*32..+31
__global__ __launch_bounds__(512, 4)
void kA(const float* __restrict__ x, const float* __restrict__ wq,
        const float* __restrict__ bq, const float* __restrict__ wk,
        const float* __restrict__ bk, unsigned short* __restrict__ y) {
  extern __shared__ char smem[];
  float* xs = (float*)smem;                              // segmented x
  unsigned short* qb = (unsigned short*)smem;            // q bf16 [128][QSTR]
  unsigned short* kt = (unsigned short*)(smem + 34816);  // kT bf16 [128][QSTR]
  float* red = (float*)(smem + 69632);

  const int bc = blockIdx.x;
  const int t = threadIdx.x;
  const float* __restrict__ xp = x + (size_t)bc * NPX;

  // stage x into segmented LDS layout
#pragma unroll
  for (int it = 0; it < 8; ++it) {
    int i = (t + it * 512) * 4;
    int rr = i >> 7, c = i & 127;
    *(float4*)&xs[GUARD + 132 * rr + 33 * (c >> 5) + (c & 31)] =
        *(const float4*)&xp[i];
  }

  const int ch = bc & 255;
  float q9[9], k9[9];
#pragma unroll
  for (int i = 0; i < 9; ++i) {
    q9[i] = sgpr_f(wq[ch * 9 + i]);
    k9[i] = sgpr_f(wk[ch * 9 + i]);
  }
  const float bqv = sgpr_f(bq[ch]), bkv = sgpr_f(bk[ch]);

  const int r = t >> 2, cb = t & 3;

  float ktm[3], qtm[3], qbm[3], kbm[3];
#pragma unroll
  for (int i = 0; i < 3; ++i) {
    ktm[i] = (r >= 6)  ? k9[i]     : 0.f;
    qtm[i] = (r >= 3)  ? q9[i]     : 0.f;
    qbm[i] = (r < 125) ? q9[6 + i] : 0.f;
    kbm[i] = (r < 122) ? k9[6 + i] : 0.f;
  }
  __syncthreads();

  const float* pcb = xs + GUARD + 33 * cb;
  const float* rm6 = pcb + 132 * (r >= 6 ? r - 6 : 0);
  const float* rm3 = pcb + 132 * (r >= 3 ? r - 3 : 0);
  const float* r00 = pcb + 132 * r;
  const float* rp3 = pcb + 132 * (r < 125 ? r + 3 : 127);
  const float* rp6 = pcb + 132 * (r < 122 ? r + 6 : 127);
  const bool mlo = (cb == 0), mhi = (cb == 3);

  float aq32[32], ak32[32];
#pragma unroll
  for (int i = 0; i < 32; ++i) { aq32[i] = bqv; ak32[i] = bkv; }
  conv_half<0>(aq32, ak32, rm6, rm3, r00, rp3, rp6, q9, k9, ktm, qtm, qbm, kbm, mlo, mhi);
  conv_half<1>(aq32 + 16, ak32 + 16, rm6, rm3, r00, rp3, rp6, q9, k9, ktm, qtm, qbm, kbm, mlo, mhi);

  float psum = 0.f;
#pragma unroll
  for (int i = 0; i < 32; ++i) psum += ak32[i];

  __syncthreads();  // all conv reads of x complete -> safe to overlay

#pragma unroll
  for (int g = 0; g < 4; ++g) {
    short8 pk;
#pragma unroll
    for (int j = 0; j < 8; ++j) pk[j] = (short)f2bf(aq32[g * 8 + j]);
    *(short8*)&qb[r * QSTR + cb * 32 + g * 8] = pk;
  }
#pragma unroll
  for (int i = 0; i < 32; ++i) kt[(cb * 32 + i) * QSTR + r] = f2bf(ak32[i]);
  __syncthreads();

  const int w = t >> 6, lane = t & 63;
  const int wr = w >> 2, wc = w & 3;
  const int r16 = lane & 15, kg = lane >> 4;
  f32x4 acc[4][2];
#pragma unroll
  for (int mi = 0; mi < 4; ++mi)
#pragma unroll
    for (int ni = 0; ni < 2; ++ni) acc[mi][ni] = (f32x4){0.f, 0.f, 0.f, 0.f};

#pragma unroll
  for (int kk = 0; kk < 4; ++kk) {
    const int kb = kk * 32 + kg * 8;
    short8 a0 = *(const short8*)&qb[(wr * 64 + 0 * 16 + r16) * QSTR + kb];
    short8 a1 = *(const short8*)&qb[(wr * 64 + 1 * 16 + r16) * QSTR + kb];
    short8 a2 = *(const short8*)&qb[(wr * 64 + 2 * 16 + r16) * QSTR + kb];
    short8 a3 = *(const short8*)&qb[(wr * 64 + 3 * 16 + r16) * QSTR + kb];
    short8 b0 = *(const short8*)&kt[(wc * 32 + 0 + r16) * QSTR + kb];
    short8 b1 = *(const short8*)&kt[(wc * 32 + 16 + r16) * QSTR + kb];
    acc[0][0] = __builtin_amdgcn_mfma_f32_16x16x32_bf16(a0, b0, acc[0][0], 0, 0, 0);
    acc[0][1] = __builtin_amdgcn_mfma_f32_16x16x32_bf16(a0, b1, acc[0][1], 0, 0, 0);
    acc[1][0] = __builtin_amdgcn_mfma_f32_16x16x32_bf16(a1, b0, acc[1][0], 0, 0, 0);
    acc[1][1] = __builtin_amdgcn_mfma_f32_16x16x32_bf16(a1, b1, acc[1][1], 0, 0, 0);
    acc[2][0] = __builtin_amdgcn_mfma_f32_16x16x32_bf16(a2, b0, acc[2][0], 0, 0, 0);
    acc[2][1] = __builtin_amdgcn_mfma_f32_16x16x32_bf16(a2, b1, acc[2][1], 0, 0, 0);
    acc[3][0] = __builtin_amdgcn_mfma_f32_16x16x32_bf16(a3, b0, acc[3][0], 0, 0, 0);
    acc[3][1] = __builtin_amdgcn_mfma_f32_16x16x32_bf16(a3, b1, acc[3][1], 0, 0, 0);
  }

  float amax = -3.402823466e38f;
#pragma unroll
  for (int mi = 0; mi < 4; ++mi)
#pragma unroll
    for (int ni = 0; ni < 2; ++ni)
#pragma unroll
      for (int j = 0; j < 4; ++j) amax = fmaxf(amax, acc[mi][ni][j]);
  amax = wave_max(amax);
  if (lane == 0) red[w] = amax;
  __syncthreads();
  float bmax = red[0];
#pragma unroll
  for (int w2 = 1; w2 < 8; ++w2) bmax = fmaxf(bmax, red[w2]);

  float es = 0.f;
#pragma unroll
  for (int mi = 0; mi < 4; ++mi)
#pragma unroll
    for (int ni = 0; ni < 2; ++ni)
#pragma unroll
      for (int j = 0; j < 4; ++j) {
        float e = __expf(acc[mi][ni][j] - bmax);
        acc[mi][ni][j] = e;
        es += e;
      }
  es = wave_sum(es);
  float ps = wave_sum(psum);
  if (lane == 0) { red[8 + w] = es; red[16 + w] = ps; }
  __syncthreads();
  float tsum = 0.f, tpool = 0.f;
#pragma unroll
  for (int w2 = 0; w2 < 8; ++w2) { tsum += red[8 + w2]; tpool += red[16 + w2]; }
  const float scale = (tpool * (1.f / 16384.f)) / tsum;

  unsigned short* __restrict__ yp = y + (size_t)bc * NPX;
#pragma unroll
  for (int mi = 0; mi < 4; ++mi)
#pragma unroll
    for (int ni = 0; ni < 2; ++ni) {
      const int col = wc * 32 + ni * 16 + r16;
#pragma unroll
      for (int j = 0; j < 4; ++j) {
        const int row = wr * 64 + mi * 16 + kg * 4 + j;
        yp[row * WDIM + col] = f2bf(acc[mi][ni][j] * scale);
      }
    }
}

// ---------------- Kernel S: s = w_sq . y via MFMA + stats + sT (bf16) -------
__global__ __launch_bounds__(256, 2)
void kS(const unsigned short* __restrict__ y, const float* __restrict__ w_sq,
        unsigned short* __restrict__ sT, float* __restrict__ partials) {
  __shared__ unsigned short yT[64][264];
  __shared__ float red[256];
  const int t = threadIdx.x;
  const int w = t >> 6, lane = t & 63;
  const int r16 = lane & 15, kg = lane >> 4;
  const int b = blockIdx.x >> 6;
  const int chunk = blockIdx.x & 63;
  const unsigned short* __restrict__ yb = y + (size_t)b * 256 * NPX;

  short8 aw[2][8];
#pragma unroll
  for (int mt = 0; mt < 2; ++mt)
#pragma unroll
    for (int ks = 0; ks < 8; ++ks) {
      const float* p = &w_sq[(mt * 16 + r16) * 256 + ks * 32 + kg * 8];
      float4 f0 = *(const float4*)p;
      float4 f1 = *(const float4*)(p + 4);
      short8 a;
      a[0] = f2bf(f0.x); a[1] = f2bf(f0.y); a[2] = f2bf(f0.z); a[3] = f2bf(f0.w);
      a[4] = f2bf(f1.x); a[5] = f2bf(f1.y); a[6] = f2bf(f1.z); a[7] = f2bf(f1.w);
      aw[mt][ks] = a;
    }

  float ssum[8], ssq[8];
#pragma unroll
  for (int i = 0; i < 8; ++i) { ssum[i] = 0.f; ssq[i] = 0.f; }

  for (int st = 0; st < 4; ++st) {
    const int p0 = chunk * 256 + st * 64;
#pragma unroll
    for (int it = 0; it < 8; ++it) {
      const int tid = it * 4 + w;
      const int cg = tid & 3, pg = tid >> 2;
      const int c = cg * 64 + lane;
      short8 v = *(const short8*)&yb[(size_t)c * NPX + p0 + pg * 8];
#pragma unroll
      for (int j = 0; j < 8; ++j) yT[pg * 8 + j][c] = (unsigned short)v[j];
    }
    __syncthreads();

    f32x4 acc[2][4];
#pragma unroll
    for (int mi = 0; mi < 2; ++mi)
#pragma unroll
      for (int ni = 0; ni < 4; ++ni) acc[mi][ni] = (f32x4){0.f, 0.f, 0.f, 0.f};

#pragma unroll
    for (int ks = 0; ks < 8; ++ks) {
#pragma unroll
      for (int ni = 0; ni < 4; ++ni) {
        short8 bv = *(const short8*)&yT[ni * 16 + r16][ks * 32 + kg * 8];
        acc[0][ni] = __builtin_amdgcn_mfma_f32_16x16x32_bf16(aw[0][ks], bv, acc[0][ni], 0, 0, 0);
        acc[1][ni] = __builtin_amdgcn_mfma_f32_16x16x32_bf16(aw[1][ks], bv, acc[1][ni], 0, 0, 0);
      }
    }

#pragma unroll
    for (int mi = 0; mi < 2; ++mi)
#pragma unroll
      for (int ni = 0; ni < 4; ++ni) {
        const int px = p0 + ni * 16 + r16;
        ushort4 pk;
#pragma unroll
        for (int j = 0; j < 4; ++j) {
          float v = acc[mi][ni][j];
          ssum[mi * 4 + j] += v;
          ssq[mi * 4 + j] += v * v;
          ((unsigned short*)&pk)[j] = f2bf(v);
        }
        *(ushort4*)&sT[((size_t)b * NPX + px) * 32 + mi * 16 + kg * 4] = pk;
      }
    __syncthreads();
  }

#pragma unroll
  for (int i = 0; i < 8; ++i) {
    float sm = ssum[i], sq = ssq[i];
#pragma unroll
    for (int m = 8; m >= 1; m >>= 1) {
      sm += __shfl_xor(sm, m);
      sq += __shfl_xor(sq, m);
    }
    if (r16 == 0) {
      const int d = (i >> 2) * 16 + kg * 4 + (i & 3);
      red[w * 64 + d] = sm;
      red[w * 64 + 32 + d] = sq;
    }
  }
  __syncthreads();
  if (t < 64) {
    float tot = red[t] + red[64 + t] + red[128 + t] + red[192 + t];
    partials[(size_t)blockIdx.x * 64 + t] = tot;
  }
}

// ---------------- Kernel R: partials -> mu, rs ------------------------------
__global__ void kR(const float* __restrict__ partials, float* __restrict__ mu_rs) {
  const int b = blockIdx.x, d = threadIdx.x;
  float sm = 0.f, sq = 0.f;
  for (int ch = 0; ch < 64; ++ch) {
    const float* pp = &partials[(size_t)(b * 64 + ch) * 64];
    sm += pp[d];
    sq += pp[32 + d];
  }
  float m = sm * (1.f / 16384.f);
  float v = sq * (1.f / 16384.f) - m * m;
  mu_rs[b * 64 + d] = m;
  mu_rs[b * 64 + 32 + d] = rsqrtf(v + 1e-5f);
}

// ---------------- Kernel O: out = w_ex . relu((s-mu)*rs) + b_ex (MFMA) ------
__global__ __launch_bounds__(256, 3)
void kO(const unsigned short* __restrict__ sT, const float* __restrict__ mu_rs,
        const float* __restrict__ w_ex, const float* __restrict__ b_ex,
        float* __restrict__ out) {
  const int t = threadIdx.x;
  const int w = t >> 6, lane = t & 63;
  const int r16 = lane & 15, kg = lane >> 4;
  const int b = blockIdx.x >> 8;
  const int p0 = (blockIdx.x & 255) * 64;
  const int c0 = w * 64;

  short8 aw[4];
#pragma unroll
  for (int mt = 0; mt < 4; ++mt) {
    const int c = c0 + mt * 16 + r16;
    const float* p = &w_ex[c * 32 + kg * 8];
    float4 f0 = *(const float4*)p;
    float4 f1 = *(const float4*)(p + 4);
    short8 a;
    a[0] = f2bf(f0.x); a[1] = f2bf(f0.y); a[2] = f2bf(f0.z); a[3] = f2bf(f0.w);
    a[4] = f2bf(f1.x); a[5] = f2bf(f1.y); a[6] = f2bf(f1.z); a[7] = f2bf(f1.w);
    aw[mt] = a;
  }

  float m8[8], r8[8];
  {
    const float* mp = &mu_rs[b * 64 + kg * 8];
    const float* rp = &mu_rs[b * 64 + 32 + kg * 8];
#pragma unroll
    for (int q = 0; q < 8; ++q) { m8[q] = mp[q]; r8[q] = rp[q]; }
  }

  f32x4 acc[4][4];
#pragma unroll
  for (int mt = 0; mt < 4; ++mt)
#pragma unroll
    for (int ni = 0; ni < 4; ++ni) acc[mt][ni] = (f32x4){0.f, 0.f, 0.f, 0.f};

#pragma unroll
  for (int ni = 0; ni < 4; ++ni) {
    const int px = p0 + ni * 16 + r16;
    short8 sv = *(const short8*)&sT[((size_t)b * NPX + px) * 32 + kg * 8];
    short8 hb;
#pragma unroll
    for (int q = 0; q < 8; ++q) {
      float f = bf2f((unsigned short)sv[q]);
      float h = fmaxf((f - m8[q]) * r8[q], 0.f);
      hb[q] = f2bf(h);
    }
#pragma unroll
    for (int mt = 0; mt < 4; ++mt)
      acc[mt][ni] = __builtin_amdgcn_mfma_f32_16x16x32_bf16(aw[mt], hb, acc[mt][ni], 0, 0, 0);
  }

  float* __restrict__ ob = out + (size_t)b * 256 * NPX;
#pragma unroll
  for (int mt = 0; mt < 4; ++mt) {
#pragma unroll
    for (int j = 0; j < 4; ++j) {
      const int c = c0 + mt * 16 + kg * 4 + j;
      const float bv = b_ex[c];
#pragma unroll
      for (int ni = 0; ni < 4; ++ni) {
        const int px = p0 + ni * 16 + r16;
        ob[(size_t)c * NPX + px] = acc[mt][ni][j] + bv;
      }
    }
  }
}

extern "C" void kernel_launch(void* const* d_in, const int* in_sizes, int n_in,
                              void* d_out, int out_size, void* d_ws, size_t ws_size,
                              hipStream_t stream) {
  (void)in_sizes; (void)n_in; (void)out_size; (void)ws_size;
  const float* x    = (const float*)d_in[0];
  const float* wq   = (const float*)d_in[1];
  const float* bq   = (const float*)d_in[2];
  const float* wk   = (const float*)d_in[3];
  const float* bk   = (const float*)d_in[4];
  const float* w_sq = (const float*)d_in[5];
  // d_in[6] = b_sq: unused — per-channel bias before InstanceNorm cancels
  const float* w_ex = (const float*)d_in[7];
  const float* b_ex = (const float*)d_in[8];
  float* out = (float*)d_out;

  unsigned short* sT = (unsigned short*)d_ws;
  float* partials = (float*)((char*)d_ws + (size_t)8 * NPX * 32 * 2);
  float* mu_rs = partials + (size_t)512 * 64;

  unsigned short* ybf = (unsigned short*)d_out;

  hipFuncSetAttribute((const void*)kA, hipFuncAttributeMaxDynamicSharedMemorySize,
                      LDS_A_BYTES);

  kA<<<2048, 512, LDS_A_BYTES, stream>>>(x, wq, bq, wk, bk, ybf);
  kS<<<512, 256, 0, stream>>>(ybf, w_sq, sT, partials);
  kR<<<8, 32, 0, stream>>>(partials, mu_rs);
  kO<<<2048, 256, 0, stream>>>(sT, mu_rs, w_ex, b_ex, out);
}

// Round 9
// 173.475 us; speedup vs baseline: 1.8656x; 1.1621x over previous
//
#include <hip/hip_runtime.h>
#include <cstdint>

#define WDIM 128
#define NPX  16384           // 128*128
#define QSTR 136             // bf16 q/kT LDS row stride (shorts), 16B-aligned rows
#define XSTR 134             // fp32 x LDS row stride: 67 b64-blocks (odd) ->
                             // window b64 group = (3r + k) mod 16: conflict-free
#define GUARD 8              // front guard (floats) for edge window reads
// x region: (8 + 134*128)*4 = 68640 B. After conv barrier overlaid by:
// qb [0,34816) | kT [34816,69632) | red at 69632. Total 69760 -> 2 blocks/CU.
#define LDS_A_BYTES 69760

typedef __attribute__((ext_vector_type(8))) short short8;
typedef __attribute__((ext_vector_type(4))) float f32x4;

__device__ __forceinline__ float wave_max(float v) {
#pragma unroll
  for (int m = 32; m >= 1; m >>= 1) v = fmaxf(v, __shfl_xor(v, m));
  return v;
}
__device__ __forceinline__ float wave_sum(float v) {
#pragma unroll
  for (int m = 32; m >= 1; m >>= 1) v += __shfl_xor(v, m);
  return v;
}
__device__ __forceinline__ unsigned short f2bf(float f) {
  uint32_t u = __float_as_uint(f);
  return (unsigned short)((u + 0x7fff + ((u >> 16) & 1)) >> 16);
}
__device__ __forceinline__ uint32_t pack2bf(float lo, float hi) {
  return (uint32_t)f2bf(lo) | ((uint32_t)f2bf(hi) << 16);
}
__device__ __forceinline__ float bf2f(unsigned short h) {
  return __uint_as_float(((uint32_t)h) << 16);
}
__device__ __forceinline__ float sgpr_f(float v) {
  return __uint_as_float(__builtin_amdgcn_readfirstlane(__float_as_uint(v)));
}

// load 28-float window (cols c0-6 .. c0+21) of one LDS row as 14 b64 reads.
__device__ __forceinline__ void load_win28(float* xw, const float* rowp,
                                           bool mlo, bool mhi) {
#pragma unroll
  for (int k = 0; k < 14; ++k)
    *(float2*)&xw[2 * k] = *(const float2*)&rowp[2 * k - 6];
  if (mlo) {  // cols -6..-1 (plane-left edge only)
#pragma unroll
    for (int j = 0; j < 6; ++j) xw[j] = 0.f;
  }
  if (mhi) {  // cols 128..133 (plane-right edge only; c0=112)
#pragma unroll
    for (int j = 22; j < 28; ++j) xw[j] = 0.f;
  }
}

template <int OFF>
__device__ __forceinline__ void tap16h(float* acc, const float* xw, float w) {
#pragma unroll
  for (int i = 0; i < 16; ++i) acc[i] = fmaf(w, xw[6 + OFF + i], acc[i]);
}

// one 16-px half of the double conv; packs results to bf16 into qd/kd (8 u32 each)
template <int H>
__device__ __forceinline__ float conv_half(
    const float* rm6, const float* rm3, const float* r00, const float* rp3,
    const float* rp6, const float* q9, const float* k9, const float* ktm,
    const float* qtm, const float* qbm, const float* kbm, bool mlo, bool mhi,
    float bqv, float bkv, uint32_t* qd, uint32_t* kd) {
  // edge-zeroing applies only to the half that actually touches the plane edge
  const bool ml = mlo && (H == 0);
  const bool mh = mhi && (H == 1);
  float aqh[16], akh[16];
#pragma unroll
  for (int i = 0; i < 16; ++i) { aqh[i] = bqv; akh[i] = bkv; }
  float xw[28];
  load_win28(xw, rm6 + 16 * H, ml, mh);
  tap16h<-6>(akh, xw, ktm[0]); tap16h<0>(akh, xw, ktm[1]); tap16h<6>(akh, xw, ktm[2]);
  load_win28(xw, rm3 + 16 * H, ml, mh);
  tap16h<-3>(aqh, xw, qtm[0]); tap16h<0>(aqh, xw, qtm[1]); tap16h<3>(aqh, xw, qtm[2]);
  load_win28(xw, r00 + 16 * H, ml, mh);
  tap16h<-3>(aqh, xw, q9[3]); tap16h<0>(aqh, xw, q9[4]); tap16h<3>(aqh, xw, q9[5]);
  tap16h<-6>(akh, xw, k9[3]); tap16h<0>(akh, xw, k9[4]); tap16h<6>(akh, xw, k9[5]);
  load_win28(xw, rp3 + 16 * H, ml, mh);
  tap16h<-3>(aqh, xw, qbm[0]); tap16h<0>(aqh, xw, qbm[1]); tap16h<3>(aqh, xw, qbm[2]);
  load_win28(xw, rp6 + 16 * H, ml, mh);
  tap16h<-6>(akh, xw, kbm[0]); tap16h<0>(akh, xw, kbm[1]); tap16h<6>(akh, xw, kbm[2]);

  float ps = 0.f;
#pragma unroll
  for (int i = 0; i < 16; ++i) ps += akh[i];
#pragma unroll
  for (int j = 0; j < 8; ++j) {
    qd[j] = pack2bf(aqh[2 * j], aqh[2 * j + 1]);
    kd[j] = pack2bf(akh[2 * j], akh[2 * j + 1]);
  }
  return ps;
}

// ---------------- Kernel A: conv -> bf16 MFMA matmul -> softmax -> *pool ----
// grid 2048 (= B*C), block 512 (8 waves). thread -> row r=t>>2, cols cb*32..+31
__global__ __launch_bounds__(512, 2)
void kA(const float* __restrict__ x, const float* __restrict__ wq,
        const float* __restrict__ bq, const float* __restrict__ wk,
        const float* __restrict__ bk, unsigned short* __restrict__ y) {
  extern __shared__ char smem[];
  float* xs = (float*)smem;                              // x, stride XSTR=134
  unsigned short* qb = (unsigned short*)smem;            // q bf16 [128][QSTR]
  unsigned short* kt = (unsigned short*)(smem + 34816);  // kT bf16 [128][QSTR]
  float* red = (float*)(smem + 69632);

  const int bc = blockIdx.x;
  const int t = threadIdx.x;
  const float* __restrict__ xp = x + (size_t)bc * NPX;

  // stage x: float4 global load -> two b64 LDS writes (odd-stride layout)
#pragma unroll
  for (int it = 0; it < 8; ++it) {
    int i = (t + it * 512) * 4;
    int rr = i >> 7, c = i & 127;
    float4 v = *(const float4*)&xp[i];
    float* dst = &xs[GUARD + XSTR * rr + c];
    *(float2*)dst = make_float2(v.x, v.y);
    *(float2*)(dst + 2) = make_float2(v.z, v.w);
  }

  const int ch = bc & 255;
  float q9[9], k9[9];
#pragma unroll
  for (int i = 0; i < 9; ++i) {
    q9[i] = sgpr_f(wq[ch * 9 + i]);
    k9[i] = sgpr_f(wk[ch * 9 + i]);
  }
  const float bqv = sgpr_f(bq[ch]), bkv = sgpr_f(bk[ch]);

  const int r = t >> 2, cb = t & 3;

  float ktm[3], qtm[3], qbm[3], kbm[3];
#pragma unroll
  for (int i = 0; i < 3; ++i) {
    ktm[i] = (r >= 6)  ? k9[i]     : 0.f;
    qtm[i] = (r >= 3)  ? q9[i]     : 0.f;
    qbm[i] = (r < 125) ? q9[6 + i] : 0.f;
    kbm[i] = (r < 122) ? k9[6 + i] : 0.f;
  }
  __syncthreads();

  const float* pcb = xs + GUARD + 32 * cb;
  const float* rm6 = pcb + XSTR * (r >= 6 ? r - 6 : 0);
  const float* rm3 = pcb + XSTR * (r >= 3 ? r - 3 : 0);
  const float* r00 = pcb + XSTR * r;
  const float* rp3 = pcb + XSTR * (r < 125 ? r + 3 : 127);
  const float* rp6 = pcb + XSTR * (r < 122 ? r + 6 : 127);
  const bool mlo = (cb == 0), mhi = (cb == 3);

  uint32_t qpk[16], kpk[16];   // q/k results, bf16-packed (2 per u32)
  float psum = 0.f;
  psum += conv_half<0>(rm6, rm3, r00, rp3, rp6, q9, k9, ktm, qtm, qbm, kbm,
                       mlo, mhi, bqv, bkv, qpk, kpk);
  psum += conv_half<1>(rm6, rm3, r00, rp3, rp6, q9, k9, ktm, qtm, qbm, kbm,
                       mlo, mhi, bqv, bkv, qpk + 8, kpk + 8);

  __syncthreads();  // all conv reads of x complete -> safe to overlay

  // write q row-major (16B stores) + kT (scalar b16)
#pragma unroll
  for (int g = 0; g < 4; ++g) {
    uint4 v = make_uint4(qpk[4 * g], qpk[4 * g + 1], qpk[4 * g + 2], qpk[4 * g + 3]);
    *(uint4*)&qb[r * QSTR + cb * 32 + g * 8] = v;
  }
#pragma unroll
  for (int i = 0; i < 32; ++i) {
    unsigned short hv = (unsigned short)(kpk[i >> 1] >> ((i & 1) * 16));
    kt[(cb * 32 + i) * QSTR + r] = hv;
  }
  __syncthreads();

  // MFMA: attn = q @ k. wave w: rows wr*64..+63, cols wc*32..+31
  const int w = t >> 6, lane = t & 63;
  const int wr = w >> 2, wc = w & 3;
  const int r16 = lane & 15, kg = lane >> 4;
  f32x4 acc[4][2];
#pragma unroll
  for (int mi = 0; mi < 4; ++mi)
#pragma unroll
    for (int ni = 0; ni < 2; ++ni) acc[mi][ni] = (f32x4){0.f, 0.f, 0.f, 0.f};

#pragma unroll
  for (int kk = 0; kk < 4; ++kk) {
    const int kb = kk * 32 + kg * 8;
    short8 a0 = *(const short8*)&qb[(wr * 64 + 0 * 16 + r16) * QSTR + kb];
    short8 a1 = *(const short8*)&qb[(wr * 64 + 1 * 16 + r16) * QSTR + kb];
    short8 a2 = *(const short8*)&qb[(wr * 64 + 2 * 16 + r16) * QSTR + kb];
    short8 a3 = *(const short8*)&qb[(wr * 64 + 3 * 16 + r16) * QSTR + kb];
    short8 b0 = *(const short8*)&kt[(wc * 32 + 0 + r16) * QSTR + kb];
    short8 b1 = *(const short8*)&kt[(wc * 32 + 16 + r16) * QSTR + kb];
    acc[0][0] = __builtin_amdgcn_mfma_f32_16x16x32_bf16(a0, b0, acc[0][0], 0, 0, 0);
    acc[0][1] = __builtin_amdgcn_mfma_f32_16x16x32_bf16(a0, b1, acc[0][1], 0, 0, 0);
    acc[1][0] = __builtin_amdgcn_mfma_f32_16x16x32_bf16(a1, b0, acc[1][0], 0, 0, 0);
    acc[1][1] = __builtin_amdgcn_mfma_f32_16x16x32_bf16(a1, b1, acc[1][1], 0, 0, 0);
    acc[2][0] = __builtin_amdgcn_mfma_f32_16x16x32_bf16(a2, b0, acc[2][0], 0, 0, 0);
    acc[2][1] = __builtin_amdgcn_mfma_f32_16x16x32_bf16(a2, b1, acc[2][1], 0, 0, 0);
    acc[3][0] = __builtin_amdgcn_mfma_f32_16x16x32_bf16(a3, b0, acc[3][0], 0, 0, 0);
    acc[3][1] = __builtin_amdgcn_mfma_f32_16x16x32_bf16(a3, b1, acc[3][1], 0, 0, 0);
  }

  // plane softmax + pool scale
  float amax = -3.402823466e38f;
#pragma unroll
  for (int mi = 0; mi < 4; ++mi)
#pragma unroll
    for (int ni = 0; ni < 2; ++ni)
#pragma unroll
      for (int j = 0; j < 4; ++j) amax = fmaxf(amax, acc[mi][ni][j]);
  amax = wave_max(amax);
  if (lane == 0) red[w] = amax;
  __syncthreads();
  float bmax = red[0];
#pragma unroll
  for (int w2 = 1; w2 < 8; ++w2) bmax = fmaxf(bmax, red[w2]);

  float es = 0.f;
#pragma unroll
  for (int mi = 0; mi < 4; ++mi)
#pragma unroll
    for (int ni = 0; ni < 2; ++ni)
#pragma unroll
      for (int j = 0; j < 4; ++j) {
        float e = __expf(acc[mi][ni][j] - bmax);
        acc[mi][ni][j] = e;
        es += e;
      }
  es = wave_sum(es);
  float ps = wave_sum(psum);
  if (lane == 0) { red[8 + w] = es; red[16 + w] = ps; }
  __syncthreads();
  float tsum = 0.f, tpool = 0.f;
#pragma unroll
  for (int w2 = 0; w2 < 8; ++w2) { tsum += red[8 + w2]; tpool += red[16 + w2]; }
  const float scale = (tpool * (1.f / 16384.f)) / tsum;

  unsigned short* __restrict__ yp = y + (size_t)bc * NPX;
#pragma unroll
  for (int mi = 0; mi < 4; ++mi)
#pragma unroll
    for (int ni = 0; ni < 2; ++ni) {
      const int col = wc * 32 + ni * 16 + r16;
#pragma unroll
      for (int j = 0; j < 4; ++j) {
        const int row = wr * 64 + mi * 16 + kg * 4 + j;
        yp[row * WDIM + col] = f2bf(acc[mi][ni][j] * scale);
      }
    }
}

// ---------------- Kernel S: s = w_sq . y via MFMA + stats + sT (bf16) -------
__global__ __launch_bounds__(256, 2)
void kS(const unsigned short* __restrict__ y, const float* __restrict__ w_sq,
        unsigned short* __restrict__ sT, float* __restrict__ partials) {
  __shared__ unsigned short yT[64][264];
  __shared__ float red[256];
  const int t = threadIdx.x;
  const int w = t >> 6, lane = t & 63;
  const int r16 = lane & 15, kg = lane >> 4;
  const int b = blockIdx.x >> 6;
  const int chunk = blockIdx.x & 63;
  const unsigned short* __restrict__ yb = y + (size_t)b * 256 * NPX;

  short8 aw[2][8];
#pragma unroll
  for (int mt = 0; mt < 2; ++mt)
#pragma unroll
    for (int ks = 0; ks < 8; ++ks) {
      const float* p = &w_sq[(mt * 16 + r16) * 256 + ks * 32 + kg * 8];
      float4 f0 = *(const float4*)p;
      float4 f1 = *(const float4*)(p + 4);
      short8 a;
      a[0] = f2bf(f0.x); a[1] = f2bf(f0.y); a[2] = f2bf(f0.z); a[3] = f2bf(f0.w);
      a[4] = f2bf(f1.x); a[5] = f2bf(f1.y); a[6] = f2bf(f1.z); a[7] = f2bf(f1.w);
      aw[mt][ks] = a;
    }

  float ssum[8], ssq[8];
#pragma unroll
  for (int i = 0; i < 8; ++i) { ssum[i] = 0.f; ssq[i] = 0.f; }

  for (int st = 0; st < 4; ++st) {
    const int p0 = chunk * 256 + st * 64;
#pragma unroll
    for (int it = 0; it < 8; ++it) {
      const int tid = it * 4 + w;
      const int cg = tid & 3, pg = tid >> 2;
      const int c = cg * 64 + lane;
      short8 v = *(const short8*)&yb[(size_t)c * NPX + p0 + pg * 8];
#pragma unroll
      for (int j = 0; j < 8; ++j) yT[pg * 8 + j][c] = (unsigned short)v[j];
    }
    __syncthreads();

    f32x4 acc[2][4];
#pragma unroll
    for (int mi = 0; mi < 2; ++mi)
#pragma unroll
      for (int ni = 0; ni < 4; ++ni) acc[mi][ni] = (f32x4){0.f, 0.f, 0.f, 0.f};

#pragma unroll
    for (int ks = 0; ks < 8; ++ks) {
#pragma unroll
      for (int ni = 0; ni < 4; ++ni) {
        short8 bv = *(const short8*)&yT[ni * 16 + r16][ks * 32 + kg * 8];
        acc[0][ni] = __builtin_amdgcn_mfma_f32_16x16x32_bf16(aw[0][ks], bv, acc[0][ni], 0, 0, 0);
        acc[1][ni] = __builtin_amdgcn_mfma_f32_16x16x32_bf16(aw[1][ks], bv, acc[1][ni], 0, 0, 0);
      }
    }

#pragma unroll
    for (int mi = 0; mi < 2; ++mi)
#pragma unroll
      for (int ni = 0; ni < 4; ++ni) {
        const int px = p0 + ni * 16 + r16;
        ushort4 pk;
#pragma unroll
        for (int j = 0; j < 4; ++j) {
          float v = acc[mi][ni][j];
          ssum[mi * 4 + j] += v;
          ssq[mi * 4 + j] += v * v;
          ((unsigned short*)&pk)[j] = f2bf(v);
        }
        *(ushort4*)&sT[((size_t)b * NPX + px) * 32 + mi * 16 + kg * 4] = pk;
      }
    __syncthreads();
  }

#pragma unroll
  for (int i = 0; i < 8; ++i) {
    float sm = ssum[i], sq = ssq[i];
#pragma unroll
    for (int m = 8; m >= 1; m >>= 1) {
      sm += __shfl_xor(sm, m);
      sq += __shfl_xor(sq, m);
    }
    if (r16 == 0) {
      const int d = (i >> 2) * 16 + kg * 4 + (i & 3);
      red[w * 64 + d] = sm;
      red[w * 64 + 32 + d] = sq;
    }
  }
  __syncthreads();
  if (t < 64) {
    float tot = red[t] + red[64 + t] + red[128 + t] + red[192 + t];
    partials[(size_t)blockIdx.x * 64 + t] = tot;
  }
}

// ---------------- Kernel R: partials -> mu, rs ------------------------------
__global__ void kR(const float* __restrict__ partials, float* __restrict__ mu_rs) {
  const int b = blockIdx.x, d = threadIdx.x;
  float sm = 0.f, sq = 0.f;
  for (int ch = 0; ch < 64; ++ch) {
    const float* pp = &partials[(size_t)(b * 64 + ch) * 64];
    sm += pp[d];
    sq += pp[32 + d];
  }
  float m = sm * (1.f / 16384.f);
  float v = sq * (1.f / 16384.f) - m * m;
  mu_rs[b * 64 + d] = m;
  mu_rs[b * 64 + 32 + d] = rsqrtf(v + 1e-5f);
}

// ---------------- Kernel O: out = w_ex . relu((s-mu)*rs) + b_ex (MFMA) ------
__global__ __launch_bounds__(256, 3)
void kO(const unsigned short* __restrict__ sT, const float* __restrict__ mu_rs,
        const float* __restrict__ w_ex, const float* __restrict__ b_ex,
        float* __restrict__ out) {
  const int t = threadIdx.x;
  const int w = t >> 6, lane = t & 63;
  const int r16 = lane & 15, kg = lane >> 4;
  const int b = blockIdx.x >> 8;
  const int p0 = (blockIdx.x & 255) * 64;
  const int c0 = w * 64;

  short8 aw[4];
#pragma unroll
  for (int mt = 0; mt < 4; ++mt) {
    const int c = c0 + mt * 16 + r16;
    const float* p = &w_ex[c * 32 + kg * 8];
    float4 f0 = *(const float4*)p;
    float4 f1 = *(const float4*)(p + 4);
    short8 a;
    a[0] = f2bf(f0.x); a[1] = f2bf(f0.y); a[2] = f2bf(f0.z); a[3] = f2bf(f0.w);
    a[4] = f2bf(f1.x); a[5] = f2bf(f1.y); a[6] = f2bf(f1.z); a[7] = f2bf(f1.w);
    aw[mt] = a;
  }

  float m8[8], r8[8];
  {
    const float* mp = &mu_rs[b * 64 + kg * 8];
    const float* rp = &mu_rs[b * 64 + 32 + kg * 8];
#pragma unroll
    for (int q = 0; q < 8; ++q) { m8[q] = mp[q]; r8[q] = rp[q]; }
  }

  f32x4 acc[4][4];
#pragma unroll
  for (int mt = 0; mt < 4; ++mt)
#pragma unroll
    for (int ni = 0; ni < 4; ++ni) acc[mt][ni] = (f32x4){0.f, 0.f, 0.f, 0.f};

#pragma unroll
  for (int ni = 0; ni < 4; ++ni) {
    const int px = p0 + ni * 16 + r16;
    short8 sv = *(const short8*)&sT[((size_t)b * NPX + px) * 32 + kg * 8];
    short8 hb;
#pragma unroll
    for (int q = 0; q < 8; ++q) {
      float f = bf2f((unsigned short)sv[q]);
      float h = fmaxf((f - m8[q]) * r8[q], 0.f);
      hb[q] = f2bf(h);
    }
#pragma unroll
    for (int mt = 0; mt < 4; ++mt)
      acc[mt][ni] = __builtin_amdgcn_mfma_f32_16x16x32_bf16(aw[mt], hb, acc[mt][ni], 0, 0, 0);
  }

  float* __restrict__ ob = out + (size_t)b * 256 * NPX;
#pragma unroll
  for (int mt = 0; mt < 4; ++mt) {
#pragma unroll
    for (int j = 0; j < 4; ++j) {
      const int c = c0 + mt * 16 + kg * 4 + j;
      const float bv = b_ex[c];
#pragma unroll
      for (int ni = 0; ni < 4; ++ni) {
        const int px = p0 + ni * 16 + r16;
        ob[(size_t)c * NPX + px] = acc[mt][ni][j] + bv;
      }
    }
  }
}

extern "C" void kernel_launch(void* const* d_in, const int* in_sizes, int n_in,
                              void* d_out, int out_size, void* d_ws, size_t ws_size,
                              hipStream_t stream) {
  (void)in_sizes; (void)n_in; (void)out_size; (void)ws_size;
  const float* x    = (const float*)d_in[0];
  const float* wq   = (const float*)d_in[1];
  const float* bq   = (const float*)d_in[2];
  const float* wk   = (const float*)d_in[3];
  const float* bk   = (const float*)d_in[4];
  const float* w_sq = (const float*)d_in[5];
  // d_in[6] = b_sq: unused — per-channel bias before InstanceNorm cancels
  const float* w_ex = (const float*)d_in[7];
  const float* b_ex = (const float*)d_in[8];
  float* out = (float*)d_out;

  unsigned short* sT = (unsigned short*)d_ws;
  float* partials = (float*)((char*)d_ws + (size_t)8 * NPX * 32 * 2);
  float* mu_rs = partials + (size_t)512 * 64;

  unsigned short* ybf = (unsigned short*)d_out;

  hipFuncSetAttribute((const void*)kA, hipFuncAttributeMaxDynamicSharedMemorySize,
                      LDS_A_BYTES);

  kA<<<2048, 512, LDS_A_BYTES, stream>>>(x, wq, bq, wk, bk, ybf);
  kS<<<512, 256, 0, stream>>>(ybf, w_sq, sT, partials);
  kR<<<8, 32, 0, stream>>>(partials, mu_rs);
  kO<<<2048, 256, 0, stream>>>(sT, mu_rs, w_ex, b_ex, out);
}

// Round 10
// 145.336 us; speedup vs baseline: 2.2268x; 1.1936x over previous
//
#include <hip/hip_runtime.h>
#include <cstdint>

#define WDIM 128
#define NPX  16384           // 128*128
#define QSTR 136             // bf16 q/kT LDS row stride (shorts), 16B-aligned rows
#define XSTR 132             // fp32 x row span: 4 segments of 33 words
#define GUARD 8              // front guard (floats) for edge window reads
// x layout: addr(r,c) = GUARD + 132*r + 33*(c>>5) + (c&31)
//   -> scalar window read bank = (4r + cb + off) mod 32: uniform 2-way = free.
// x region (8+132*128)*4 = 67616 B; after conv barrier overlaid by:
// qb [0,34816) | kT [34816,69632) | red at 69632. Total 69760 -> 2 blocks/CU.
#define LDS_A_BYTES 69760

typedef __attribute__((ext_vector_type(8))) short short8;
typedef __attribute__((ext_vector_type(4))) float f32x4;

__device__ __forceinline__ float wave_max(float v) {
#pragma unroll
  for (int m = 32; m >= 1; m >>= 1) v = fmaxf(v, __shfl_xor(v, m));
  return v;
}
__device__ __forceinline__ float wave_sum(float v) {
#pragma unroll
  for (int m = 32; m >= 1; m >>= 1) v += __shfl_xor(v, m);
  return v;
}
__device__ __forceinline__ unsigned short f2bf(float f) {
  uint32_t u = __float_as_uint(f);
  return (unsigned short)((u + 0x7fff + ((u >> 16) & 1)) >> 16);
}
__device__ __forceinline__ uint32_t pack2bf(float lo, float hi) {
  return (uint32_t)f2bf(lo) | ((uint32_t)f2bf(hi) << 16);
}
__device__ __forceinline__ float bf2f(unsigned short h) {
  return __uint_as_float(((uint32_t)h) << 16);
}
__device__ __forceinline__ float sgpr_f(float v) {
  return __uint_as_float(__builtin_amdgcn_readfirstlane(__float_as_uint(v)));
}

// load one 28-float window (16 px + 6 halo each side) of a segmented row.
// Scalar b32 reads; offsets hop the 33-word segment boundaries (round-7 math,
// correctness-proven). Edge zeroing only on the half touching the plane edge.
template <int H>
__device__ __forceinline__ void load_win28(float* xw, const float* rowp,
                                           bool ml, bool mh) {
#pragma unroll
  for (int w = 0; w < 28; ++w) {
    int off;
    if (H == 0) off = (w < 6) ? (w - 7) : (w - 6);
    else        off = (w < 22) ? (w + 10) : (w + 11);
    xw[w] = rowp[off];
  }
  if (H == 0 && ml) {
#pragma unroll
    for (int j = 0; j < 6; ++j) xw[j] = 0.f;
  }
  if (H == 1 && mh) {
#pragma unroll
    for (int j = 22; j < 28; ++j) xw[j] = 0.f;
  }
}

template <int OFF>
__device__ __forceinline__ void tap16h(float* acc, const float* xw, float w) {
#pragma unroll
  for (int i = 0; i < 16; ++i) acc[i] = fmaf(w, xw[6 + OFF + i], acc[i]);
}

// one 16-px half of the double conv; packs results to bf16 into qd/kd (8 u32 each)
template <int H>
__device__ __forceinline__ float conv_half(
    const float* rm6, const float* rm3, const float* r00, const float* rp3,
    const float* rp6, const float* q9, const float* k9, const float* ktm,
    const float* qtm, const float* qbm, const float* kbm, bool mlo, bool mhi,
    float bqv, float bkv, uint32_t* qd, uint32_t* kd) {
  const bool ml = mlo && (H == 0);
  const bool mh = mhi && (H == 1);
  float aqh[16], akh[16];
#pragma unroll
  for (int i = 0; i < 16; ++i) { aqh[i] = bqv; akh[i] = bkv; }
  float xw[28];
  load_win28<H>(xw, rm6, ml, mh);
  tap16h<-6>(akh, xw, ktm[0]); tap16h<0>(akh, xw, ktm[1]); tap16h<6>(akh, xw, ktm[2]);
  load_win28<H>(xw, rm3, ml, mh);
  tap16h<-3>(aqh, xw, qtm[0]); tap16h<0>(aqh, xw, qtm[1]); tap16h<3>(aqh, xw, qtm[2]);
  load_win28<H>(xw, r00, ml, mh);
  tap16h<-3>(aqh, xw, q9[3]); tap16h<0>(aqh, xw, q9[4]); tap16h<3>(aqh, xw, q9[5]);
  tap16h<-6>(akh, xw, k9[3]); tap16h<0>(akh, xw, k9[4]); tap16h<6>(akh, xw, k9[5]);
  load_win28<H>(xw, rp3, ml, mh);
  tap16h<-3>(aqh, xw, qbm[0]); tap16h<0>(aqh, xw, qbm[1]); tap16h<3>(aqh, xw, qbm[2]);
  load_win28<H>(xw, rp6, ml, mh);
  tap16h<-6>(akh, xw, kbm[0]); tap16h<0>(akh, xw, kbm[1]); tap16h<6>(akh, xw, kbm[2]);

  float ps = 0.f;
#pragma unroll
  for (int i = 0; i < 16; ++i) ps += akh[i];
#pragma unroll
  for (int j = 0; j < 8; ++j) {
    qd[j] = pack2bf(aqh[2 * j], aqh[2 * j + 1]);
    kd[j] = pack2bf(akh[2 * j], akh[2 * j + 1]);
  }
  return ps;
}

// ---------------- Kernel A: conv -> bf16 MFMA matmul -> softmax -> *pool ----
// grid 2048 (= B*C), block 512 (8 waves). thread -> row r=t>>2, cols cb*32..+31
__global__ __launch_bounds__(512, 2)
void kA(const float* __restrict__ x, const float* __restrict__ wq,
        const float* __restrict__ bq, const float* __restrict__ wk,
        const float* __restrict__ bk, unsigned short* __restrict__ y) {
  extern __shared__ char smem[];
  float* xs = (float*)smem;                              // segmented x
  unsigned short* qb = (unsigned short*)smem;            // q bf16 [128][QSTR]
  unsigned short* kt = (unsigned short*)(smem + 34816);  // kT bf16 [128][QSTR]
  float* red = (float*)(smem + 69632);

  const int bc = blockIdx.x;
  const int t = threadIdx.x;
  const float* __restrict__ xp = x + (size_t)bc * NPX;

  // stage x into segmented LDS layout (4 scalar stores; segment base is odd)
#pragma unroll
  for (int it = 0; it < 8; ++it) {
    int i = (t + it * 512) * 4;
    int rr = i >> 7, c = i & 127;
    float4 v = *(const float4*)&xp[i];
    float* dst = &xs[GUARD + 132 * rr + 33 * (c >> 5) + (c & 31)];
    dst[0] = v.x; dst[1] = v.y; dst[2] = v.z; dst[3] = v.w;
  }

  const int ch = bc & 255;
  float q9[9], k9[9];
#pragma unroll
  for (int i = 0; i < 9; ++i) {
    q9[i] = sgpr_f(wq[ch * 9 + i]);
    k9[i] = sgpr_f(wk[ch * 9 + i]);
  }
  const float bqv = sgpr_f(bq[ch]), bkv = sgpr_f(bk[ch]);

  const int r = t >> 2, cb = t & 3;

  // masked weights for out-of-plane rows (rows clamped; weight=0 kills them)
  float ktm[3], qtm[3], qbm[3], kbm[3];
#pragma unroll
  for (int i = 0; i < 3; ++i) {
    ktm[i] = (r >= 6)  ? k9[i]     : 0.f;
    qtm[i] = (r >= 3)  ? q9[i]     : 0.f;
    qbm[i] = (r < 125) ? q9[6 + i] : 0.f;
    kbm[i] = (r < 122) ? k9[6 + i] : 0.f;
  }
  __syncthreads();

  const float* pcb = xs + GUARD + 33 * cb;   // per-thread segment base
  const float* rm6 = pcb + XSTR * (r >= 6 ? r - 6 : 0);
  const float* rm3 = pcb + XSTR * (r >= 3 ? r - 3 : 0);
  const float* r00 = pcb + XSTR * r;
  const float* rp3 = pcb + XSTR * (r < 125 ? r + 3 : 127);
  const float* rp6 = pcb + XSTR * (r < 122 ? r + 6 : 127);
  const bool mlo = (cb == 0), mhi = (cb == 3);

  uint32_t qpk[16], kpk[16];   // q/k results, bf16-packed (2 per u32)
  float psum = 0.f;
  psum += conv_half<0>(rm6, rm3, r00, rp3, rp6, q9, k9, ktm, qtm, qbm, kbm,
                       mlo, mhi, bqv, bkv, qpk, kpk);
  psum += conv_half<1>(rm6, rm3, r00, rp3, rp6, q9, k9, ktm, qtm, qbm, kbm,
                       mlo, mhi, bqv, bkv, qpk + 8, kpk + 8);

  __syncthreads();  // all conv reads of x complete -> safe to overlay

  // write q row-major (16B stores) + kT (scalar b16)
#pragma unroll
  for (int g = 0; g < 4; ++g) {
    uint4 v = make_uint4(qpk[4 * g], qpk[4 * g + 1], qpk[4 * g + 2], qpk[4 * g + 3]);
    *(uint4*)&qb[r * QSTR + cb * 32 + g * 8] = v;
  }
#pragma unroll
  for (int i = 0; i < 32; ++i) {
    unsigned short hv = (unsigned short)(kpk[i >> 1] >> ((i & 1) * 16));
    kt[(cb * 32 + i) * QSTR + r] = hv;
  }
  __syncthreads();

  // MFMA: attn = q @ k. wave w: rows wr*64..+63, cols wc*32..+31
  const int w = t >> 6, lane = t & 63;
  const int wr = w >> 2, wc = w & 3;
  const int r16 = lane & 15, kg = lane >> 4;
  f32x4 acc[4][2];
#pragma unroll
  for (int mi = 0; mi < 4; ++mi)
#pragma unroll
    for (int ni = 0; ni < 2; ++ni) acc[mi][ni] = (f32x4){0.f, 0.f, 0.f, 0.f};

#pragma unroll
  for (int kk = 0; kk < 4; ++kk) {
    const int kb = kk * 32 + kg * 8;
    short8 a0 = *(const short8*)&qb[(wr * 64 + 0 * 16 + r16) * QSTR + kb];
    short8 a1 = *(const short8*)&qb[(wr * 64 + 1 * 16 + r16) * QSTR + kb];
    short8 a2 = *(const short8*)&qb[(wr * 64 + 2 * 16 + r16) * QSTR + kb];
    short8 a3 = *(const short8*)&qb[(wr * 64 + 3 * 16 + r16) * QSTR + kb];
    short8 b0 = *(const short8*)&kt[(wc * 32 + 0 + r16) * QSTR + kb];
    short8 b1 = *(const short8*)&kt[(wc * 32 + 16 + r16) * QSTR + kb];
    acc[0][0] = __builtin_amdgcn_mfma_f32_16x16x32_bf16(a0, b0, acc[0][0], 0, 0, 0);
    acc[0][1] = __builtin_amdgcn_mfma_f32_16x16x32_bf16(a0, b1, acc[0][1], 0, 0, 0);
    acc[1][0] = __builtin_amdgcn_mfma_f32_16x16x32_bf16(a1, b0, acc[1][0], 0, 0, 0);
    acc[1][1] = __builtin_amdgcn_mfma_f32_16x16x32_bf16(a1, b1, acc[1][1], 0, 0, 0);
    acc[2][0] = __builtin_amdgcn_mfma_f32_16x16x32_bf16(a2, b0, acc[2][0], 0, 0, 0);
    acc[2][1] = __builtin_amdgcn_mfma_f32_16x16x32_bf16(a2, b1, acc[2][1], 0, 0, 0);
    acc[3][0] = __builtin_amdgcn_mfma_f32_16x16x32_bf16(a3, b0, acc[3][0], 0, 0, 0);
    acc[3][1] = __builtin_amdgcn_mfma_f32_16x16x32_bf16(a3, b1, acc[3][1], 0, 0, 0);
  }

  // plane softmax + pool scale
  float amax = -3.402823466e38f;
#pragma unroll
  for (int mi = 0; mi < 4; ++mi)
#pragma unroll
    for (int ni = 0; ni < 2; ++ni)
#pragma unroll
      for (int j = 0; j < 4; ++j) amax = fmaxf(amax, acc[mi][ni][j]);
  amax = wave_max(amax);
  if (lane == 0) red[w] = amax;
  __syncthreads();
  float bmax = red[0];
#pragma unroll
  for (int w2 = 1; w2 < 8; ++w2) bmax = fmaxf(bmax, red[w2]);

  float es = 0.f;
#pragma unroll
  for (int mi = 0; mi < 4; ++mi)
#pragma unroll
    for (int ni = 0; ni < 2; ++ni)
#pragma unroll
      for (int j = 0; j < 4; ++j) {
        float e = __expf(acc[mi][ni][j] - bmax);
        acc[mi][ni][j] = e;
        es += e;
      }
  es = wave_sum(es);
  float ps = wave_sum(psum);
  if (lane == 0) { red[8 + w] = es; red[16 + w] = ps; }
  __syncthreads();
  float tsum = 0.f, tpool = 0.f;
#pragma unroll
  for (int w2 = 0; w2 < 8; ++w2) { tsum += red[8 + w2]; tpool += red[16 + w2]; }
  const float scale = (tpool * (1.f / 16384.f)) / tsum;

  unsigned short* __restrict__ yp = y + (size_t)bc * NPX;
#pragma unroll
  for (int mi = 0; mi < 4; ++mi)
#pragma unroll
    for (int ni = 0; ni < 2; ++ni) {
      const int col = wc * 32 + ni * 16 + r16;
#pragma unroll
      for (int j = 0; j < 4; ++j) {
        const int row = wr * 64 + mi * 16 + kg * 4 + j;
        yp[row * WDIM + col] = f2bf(acc[mi][ni][j] * scale);
      }
    }
}

// ---------------- Kernel S: s = w_sq . y via MFMA + stats + sT (bf16) -------
__global__ __launch_bounds__(256, 2)
void kS(const unsigned short* __restrict__ y, const float* __restrict__ w_sq,
        unsigned short* __restrict__ sT, float* __restrict__ partials) {
  __shared__ unsigned short yT[64][264];
  __shared__ float red[256];
  const int t = threadIdx.x;
  const int w = t >> 6, lane = t & 63;
  const int r16 = lane & 15, kg = lane >> 4;
  const int b = blockIdx.x >> 6;
  const int chunk = blockIdx.x & 63;
  const unsigned short* __restrict__ yb = y + (size_t)b * 256 * NPX;

  short8 aw[2][8];
#pragma unroll
  for (int mt = 0; mt < 2; ++mt)
#pragma unroll
    for (int ks = 0; ks < 8; ++ks) {
      const float* p = &w_sq[(mt * 16 + r16) * 256 + ks * 32 + kg * 8];
      float4 f0 = *(const float4*)p;
      float4 f1 = *(const float4*)(p + 4);
      short8 a;
      a[0] = f2bf(f0.x); a[1] = f2bf(f0.y); a[2] = f2bf(f0.z); a[3] = f2bf(f0.w);
      a[4] = f2bf(f1.x); a[5] = f2bf(f1.y); a[6] = f2bf(f1.z); a[7] = f2bf(f1.w);
      aw[mt][ks] = a;
    }

  float ssum[8], ssq[8];
#pragma unroll
  for (int i = 0; i < 8; ++i) { ssum[i] = 0.f; ssq[i] = 0.f; }

  for (int st = 0; st < 4; ++st) {
    const int p0 = chunk * 256 + st * 64;
#pragma unroll
    for (int it = 0; it < 8; ++it) {
      const int tid = it * 4 + w;
      const int cg = tid & 3, pg = tid >> 2;
      const int c = cg * 64 + lane;
      short8 v = *(const short8*)&yb[(size_t)c * NPX + p0 + pg * 8];
#pragma unroll
      for (int j = 0; j < 8; ++j) yT[pg * 8 + j][c] = (unsigned short)v[j];
    }
    __syncthreads();

    f32x4 acc[2][4];
#pragma unroll
    for (int mi = 0; mi < 2; ++mi)
#pragma unroll
      for (int ni = 0; ni < 4; ++ni) acc[mi][ni] = (f32x4){0.f, 0.f, 0.f, 0.f};

#pragma unroll
    for (int ks = 0; ks < 8; ++ks) {
#pragma unroll
      for (int ni = 0; ni < 4; ++ni) {
        short8 bv = *(const short8*)&yT[ni * 16 + r16][ks * 32 + kg * 8];
        acc[0][ni] = __builtin_amdgcn_mfma_f32_16x16x32_bf16(aw[0][ks], bv, acc[0][ni], 0, 0, 0);
        acc[1][ni] = __builtin_amdgcn_mfma_f32_16x16x32_bf16(aw[1][ks], bv, acc[1][ni], 0, 0, 0);
      }
    }

#pragma unroll
    for (int mi = 0; mi < 2; ++mi)
#pragma unroll
      for (int ni = 0; ni < 4; ++ni) {
        const int px = p0 + ni * 16 + r16;
        ushort4 pk;
#pragma unroll
        for (int j = 0; j < 4; ++j) {
          float v = acc[mi][ni][j];
          ssum[mi * 4 + j] += v;
          ssq[mi * 4 + j] += v * v;
          ((unsigned short*)&pk)[j] = f2bf(v);
        }
        *(ushort4*)&sT[((size_t)b * NPX + px) * 32 + mi * 16 + kg * 4] = pk;
      }
    __syncthreads();
  }

#pragma unroll
  for (int i = 0; i < 8; ++i) {
    float sm = ssum[i], sq = ssq[i];
#pragma unroll
    for (int m = 8; m >= 1; m >>= 1) {
      sm += __shfl_xor(sm, m);
      sq += __shfl_xor(sq, m);
    }
    if (r16 == 0) {
      const int d = (i >> 2) * 16 + kg * 4 + (i & 3);
      red[w * 64 + d] = sm;
      red[w * 64 + 32 + d] = sq;
    }
  }
  __syncthreads();
  if (t < 64) {
    float tot = red[t] + red[64 + t] + red[128 + t] + red[192 + t];
    partials[(size_t)blockIdx.x * 64 + t] = tot;
  }
}

// ---------------- Kernel R: partials -> mu, rs ------------------------------
__global__ void kR(const float* __restrict__ partials, float* __restrict__ mu_rs) {
  const int b = blockIdx.x, d = threadIdx.x;
  float sm = 0.f, sq = 0.f;
  for (int ch = 0; ch < 64; ++ch) {
    const float* pp = &partials[(size_t)(b * 64 + ch) * 64];
    sm += pp[d];
    sq += pp[32 + d];
  }
  float m = sm * (1.f / 16384.f);
  float v = sq * (1.f / 16384.f) - m * m;
  mu_rs[b * 64 + d] = m;
  mu_rs[b * 64 + 32 + d] = rsqrtf(v + 1e-5f);
}

// ---------------- Kernel O: out = w_ex . relu((s-mu)*rs) + b_ex (MFMA) ------
__global__ __launch_bounds__(256, 3)
void kO(const unsigned short* __restrict__ sT, const float* __restrict__ mu_rs,
        const float* __restrict__ w_ex, const float* __restrict__ b_ex,
        float* __restrict__ out) {
  const int t = threadIdx.x;
  const int w = t >> 6, lane = t & 63;
  const int r16 = lane & 15, kg = lane >> 4;
  const int b = blockIdx.x >> 8;
  const int p0 = (blockIdx.x & 255) * 64;
  const int c0 = w * 64;

  short8 aw[4];
#pragma unroll
  for (int mt = 0; mt < 4; ++mt) {
    const int c = c0 + mt * 16 + r16;
    const float* p = &w_ex[c * 32 + kg * 8];
    float4 f0 = *(const float4*)p;
    float4 f1 = *(const float4*)(p + 4);
    short8 a;
    a[0] = f2bf(f0.x); a[1] = f2bf(f0.y); a[2] = f2bf(f0.z); a[3] = f2bf(f0.w);
    a[4] = f2bf(f1.x); a[5] = f2bf(f1.y); a[6] = f2bf(f1.z); a[7] = f2bf(f1.w);
    aw[mt] = a;
  }

  float m8[8], r8[8];
  {
    const float* mp = &mu_rs[b * 64 + kg * 8];
    const float* rp = &mu_rs[b * 64 + 32 + kg * 8];
#pragma unroll
    for (int q = 0; q < 8; ++q) { m8[q] = mp[q]; r8[q] = rp[q]; }
  }

  f32x4 acc[4][4];
#pragma unroll
  for (int mt = 0; mt < 4; ++mt)
#pragma unroll
    for (int ni = 0; ni < 4; ++ni) acc[mt][ni] = (f32x4){0.f, 0.f, 0.f, 0.f};

#pragma unroll
  for (int ni = 0; ni < 4; ++ni) {
    const int px = p0 + ni * 16 + r16;
    short8 sv = *(const short8*)&sT[((size_t)b * NPX + px) * 32 + kg * 8];
    short8 hb;
#pragma unroll
    for (int q = 0; q < 8; ++q) {
      float f = bf2f((unsigned short)sv[q]);
      float h = fmaxf((f - m8[q]) * r8[q], 0.f);
      hb[q] = f2bf(h);
    }
#pragma unroll
    for (int mt = 0; mt < 4; ++mt)
      acc[mt][ni] = __builtin_amdgcn_mfma_f32_16x16x32_bf16(aw[mt], hb, acc[mt][ni], 0, 0, 0);
  }

  float* __restrict__ ob = out + (size_t)b * 256 * NPX;
#pragma unroll
  for (int mt = 0; mt < 4; ++mt) {
#pragma unroll
    for (int j = 0; j < 4; ++j) {
      const int c = c0 + mt * 16 + kg * 4 + j;
      const float bv = b_ex[c];
#pragma unroll
      for (int ni = 0; ni < 4; ++ni) {
        const int px = p0 + ni * 16 + r16;
        ob[(size_t)c * NPX + px] = acc[mt][ni][j] + bv;
      }
    }
  }
}

extern "C" void kernel_launch(void* const* d_in, const int* in_sizes, int n_in,
                              void* d_out, int out_size, void* d_ws, size_t ws_size,
                              hipStream_t stream) {
  (void)in_sizes; (void)n_in; (void)out_size; (void)ws_size;
  const float* x    = (const float*)d_in[0];
  const float* wq   = (const float*)d_in[1];
  const float* bq   = (const float*)d_in[2];
  const float* wk   = (const float*)d_in[3];
  const float* bk   = (const float*)d_in[4];
  const float* w_sq = (const float*)d_in[5];
  // d_in[6] = b_sq: unused — per-channel bias before InstanceNorm cancels
  const float* w_ex = (const float*)d_in[7];
  const float* b_ex = (const float*)d_in[8];
  float* out = (float*)d_out;

  unsigned short* sT = (unsigned short*)d_ws;
  float* partials = (float*)((char*)d_ws + (size_t)8 * NPX * 32 * 2);
  float* mu_rs = partials + (size_t)512 * 64;

  unsigned short* ybf = (unsigned short*)d_out;

  hipFuncSetAttribute((const void*)kA, hipFuncAttributeMaxDynamicSharedMemorySize,
                      LDS_A_BYTES);

  kA<<<2048, 512, LDS_A_BYTES, stream>>>(x, wq, bq, wk, bk, ybf);
  kS<<<512, 256, 0, stream>>>(ybf, w_sq, sT, partials);
  kR<<<8, 32, 0, stream>>>(partials, mu_rs);
  kO<<<2048, 256, 0, stream>>>(sT, mu_rs, w_ex, b_ex, out);
}

// Round 11
// 144.972 us; speedup vs baseline: 2.2324x; 1.0025x over previous
//
#include <hip/hip_runtime.h>
#include <cstdint>

#define WDIM 128
#define NPX  16384           // 128*128
#define QSTR 136             // bf16 q/kT LDS row stride (shorts), 16B-aligned rows
#define XSTR 132             // fp32 x row span: 4 segments of 33 words
#define GUARD 8              // front guard (floats) for edge window reads
// x layout: addr(r,c) = GUARD + 132*r + 33*(c>>5) + (c&31)
//   -> scalar window read bank = (4r + cb + off) mod 32: uniform 2-way, free.
// x region (8+132*128)*4 = 67616 B; after conv barrier overlaid by:
// qb [0,34816) | kT [34816,69632) | red at 69632. Total 69760 -> 2 blocks/CU.
#define LDS_A_BYTES 69760

typedef __attribute__((ext_vector_type(8))) short short8;
typedef __attribute__((ext_vector_type(4))) float f32x4;

__device__ __forceinline__ float wave_max(float v) {
#pragma unroll
  for (int m = 32; m >= 1; m >>= 1) v = fmaxf(v, __shfl_xor(v, m));
  return v;
}
__device__ __forceinline__ float wave_sum(float v) {
#pragma unroll
  for (int m = 32; m >= 1; m >>= 1) v += __shfl_xor(v, m);
  return v;
}
__device__ __forceinline__ unsigned short f2bf(float f) {
  uint32_t u = __float_as_uint(f);
  return (unsigned short)((u + 0x7fff + ((u >> 16) & 1)) >> 16);
}
__device__ __forceinline__ uint32_t pack2bf(float lo, float hi) {
  return (uint32_t)f2bf(lo) | ((uint32_t)f2bf(hi) << 16);
}
__device__ __forceinline__ float bf2f(unsigned short h) {
  return __uint_as_float(((uint32_t)h) << 16);
}
__device__ __forceinline__ float sgpr_f(float v) {
  return __uint_as_float(__builtin_amdgcn_readfirstlane(__float_as_uint(v)));
}

// load one 28-float window (16 px + 6 halo each side) of a segmented row.
// Scalar b32 reads; offsets hop the 33-word segment boundaries.
template <int H>
__device__ __forceinline__ void load_win28(float* xw, const float* rowp,
                                           bool ml, bool mh) {
#pragma unroll
  for (int w = 0; w < 28; ++w) {
    int off;
    if (H == 0) off = (w < 6) ? (w - 7) : (w - 6);
    else        off = (w < 22) ? (w + 10) : (w + 11);
    xw[w] = rowp[off];
  }
  if (H == 0 && ml) {
#pragma unroll
    for (int j = 0; j < 6; ++j) xw[j] = 0.f;
  }
  if (H == 1 && mh) {
#pragma unroll
    for (int j = 22; j < 28; ++j) xw[j] = 0.f;
  }
}

template <int OFF>
__device__ __forceinline__ void tap16h(float* acc, const float* xw, float w) {
#pragma unroll
  for (int i = 0; i < 16; ++i) acc[i] = fmaf(w, xw[6 + OFF + i], acc[i]);
}

// one 16-px half of the double conv; packs results to bf16 into qd/kd.
// Row guards are branches (wave-quasi-uniform; divergent only in waves 0/7)
// instead of masked weights -> 12 fewer VGPRs and skipped edge work.
template <int H>
__device__ __forceinline__ float conv_half(
    const float* rm6, const float* rm3, const float* r00, const float* rp3,
    const float* rp6, const float* q9, const float* k9, int r, bool mlo,
    bool mhi, float bqv, float bkv, uint32_t* qd, uint32_t* kd) {
  const bool ml = mlo && (H == 0);
  const bool mh = mhi && (H == 1);
  float aqh[16], akh[16];
#pragma unroll
  for (int i = 0; i < 16; ++i) { aqh[i] = bqv; akh[i] = bkv; }
  float xw[28];
  if (r >= 6) {
    load_win28<H>(xw, rm6, ml, mh);
    tap16h<-6>(akh, xw, k9[0]); tap16h<0>(akh, xw, k9[1]); tap16h<6>(akh, xw, k9[2]);
  }
  if (r >= 3) {
    load_win28<H>(xw, rm3, ml, mh);
    tap16h<-3>(aqh, xw, q9[0]); tap16h<0>(aqh, xw, q9[1]); tap16h<3>(aqh, xw, q9[2]);
  }
  {
    load_win28<H>(xw, r00, ml, mh);
    tap16h<-3>(aqh, xw, q9[3]); tap16h<0>(aqh, xw, q9[4]); tap16h<3>(aqh, xw, q9[5]);
    tap16h<-6>(akh, xw, k9[3]); tap16h<0>(akh, xw, k9[4]); tap16h<6>(akh, xw, k9[5]);
  }
  if (r < 125) {
    load_win28<H>(xw, rp3, ml, mh);
    tap16h<-3>(aqh, xw, q9[6]); tap16h<0>(aqh, xw, q9[7]); tap16h<3>(aqh, xw, q9[8]);
  }
  if (r < 122) {
    load_win28<H>(xw, rp6, ml, mh);
    tap16h<-6>(akh, xw, k9[6]); tap16h<0>(akh, xw, k9[7]); tap16h<6>(akh, xw, k9[8]);
  }

  float ps = 0.f;
#pragma unroll
  for (int i = 0; i < 16; ++i) ps += akh[i];
#pragma unroll
  for (int j = 0; j < 8; ++j) {
    qd[j] = pack2bf(aqh[2 * j], aqh[2 * j + 1]);
    kd[j] = pack2bf(akh[2 * j], akh[2 * j + 1]);
  }
  return ps;
}

// ---------------- Kernel A: conv -> bf16 MFMA matmul -> softmax -> *pool ----
// grid 2048 (= B*C), block 512 (8 waves). thread -> row r=t>>2, cols cb*32..+31
__global__ __launch_bounds__(512, 2)
void kA(const float* __restrict__ x, const float* __restrict__ wq,
        const float* __restrict__ bq, const float* __restrict__ wk,
        const float* __restrict__ bk, unsigned short* __restrict__ y) {
  extern __shared__ char smem[];
  float* xs = (float*)smem;                              // segmented x
  unsigned short* qb = (unsigned short*)smem;            // q bf16 [128][QSTR]
  unsigned short* kt = (unsigned short*)(smem + 34816);  // kT bf16 [128][QSTR]
  float* red = (float*)(smem + 69632);

  const int bc = blockIdx.x;
  const int t = threadIdx.x;
  const float* __restrict__ xp = x + (size_t)bc * NPX;

  // stage x into segmented LDS layout (4 scalar stores; segment base is odd)
#pragma unroll
  for (int it = 0; it < 8; ++it) {
    int i = (t + it * 512) * 4;
    int rr = i >> 7, c = i & 127;
    float4 v = *(const float4*)&xp[i];
    float* dst = &xs[GUARD + 132 * rr + 33 * (c >> 5) + (c & 31)];
    dst[0] = v.x; dst[1] = v.y; dst[2] = v.z; dst[3] = v.w;
  }

  const int ch = bc & 255;
  float q9[9], k9[9];
#pragma unroll
  for (int i = 0; i < 9; ++i) {
    q9[i] = sgpr_f(wq[ch * 9 + i]);
    k9[i] = sgpr_f(wk[ch * 9 + i]);
  }
  const float bqv = sgpr_f(bq[ch]), bkv = sgpr_f(bk[ch]);

  const int r = t >> 2, cb = t & 3;
  __syncthreads();

  const float* pcb = xs + GUARD + 33 * cb;   // per-thread segment base
  const float* rm6 = pcb + XSTR * (r - 6);   // only dereferenced when r>=6
  const float* rm3 = pcb + XSTR * (r - 3);
  const float* r00 = pcb + XSTR * r;
  const float* rp3 = pcb + XSTR * (r + 3);
  const float* rp6 = pcb + XSTR * (r + 6);
  const bool mlo = (cb == 0), mhi = (cb == 3);

  uint32_t qpk[16], kpk[16];   // q/k results, bf16-packed (2 per u32)
  float psum = 0.f;
  psum += conv_half<0>(rm6, rm3, r00, rp3, rp6, q9, k9, r,
                       mlo, mhi, bqv, bkv, qpk, kpk);
  psum += conv_half<1>(rm6, rm3, r00, rp3, rp6, q9, k9, r,
                       mlo, mhi, bqv, bkv, qpk + 8, kpk + 8);

  __syncthreads();  // all conv reads of x complete -> safe to overlay

  // write q row-major (16B stores) + kT (b16, cb-rotated order -> 2-way banks)
#pragma unroll
  for (int g = 0; g < 4; ++g) {
    uint4 v = make_uint4(qpk[4 * g], qpk[4 * g + 1], qpk[4 * g + 2], qpk[4 * g + 3]);
    *(uint4*)&qb[r * QSTR + cb * 32 + g * 8] = v;
  }
#pragma unroll
  for (int ii = 0; ii < 32; ++ii) {
    const int i = (ii + cb) & 31;
    unsigned short hv = (unsigned short)(kpk[i >> 1] >> ((i & 1) * 16));
    kt[(cb * 32 + i) * QSTR + r] = hv;
  }
  __syncthreads();

  // MFMA: attn = q @ k. wave w: rows wr*64..+63, cols wc*32..+31
  const int w = t >> 6, lane = t & 63;
  const int wr = w >> 2, wc = w & 3;
  const int r16 = lane & 15, kg = lane >> 4;
  f32x4 acc[4][2];
#pragma unroll
  for (int mi = 0; mi < 4; ++mi)
#pragma unroll
    for (int ni = 0; ni < 2; ++ni) acc[mi][ni] = (f32x4){0.f, 0.f, 0.f, 0.f};

#pragma unroll
  for (int kk = 0; kk < 4; ++kk) {
    const int kb = kk * 32 + kg * 8;
    short8 a0 = *(const short8*)&qb[(wr * 64 + 0 * 16 + r16) * QSTR + kb];
    short8 a1 = *(const short8*)&qb[(wr * 64 + 1 * 16 + r16) * QSTR + kb];
    short8 a2 = *(const short8*)&qb[(wr * 64 + 2 * 16 + r16) * QSTR + kb];
    short8 a3 = *(const short8*)&qb[(wr * 64 + 3 * 16 + r16) * QSTR + kb];
    short8 b0 = *(const short8*)&kt[(wc * 32 + 0 + r16) * QSTR + kb];
    short8 b1 = *(const short8*)&kt[(wc * 32 + 16 + r16) * QSTR + kb];
    acc[0][0] = __builtin_amdgcn_mfma_f32_16x16x32_bf16(a0, b0, acc[0][0], 0, 0, 0);
    acc[0][1] = __builtin_amdgcn_mfma_f32_16x16x32_bf16(a0, b1, acc[0][1], 0, 0, 0);
    acc[1][0] = __builtin_amdgcn_mfma_f32_16x16x32_bf16(a1, b0, acc[1][0], 0, 0, 0);
    acc[1][1] = __builtin_amdgcn_mfma_f32_16x16x32_bf16(a1, b1, acc[1][1], 0, 0, 0);
    acc[2][0] = __builtin_amdgcn_mfma_f32_16x16x32_bf16(a2, b0, acc[2][0], 0, 0, 0);
    acc[2][1] = __builtin_amdgcn_mfma_f32_16x16x32_bf16(a2, b1, acc[2][1], 0, 0, 0);
    acc[3][0] = __builtin_amdgcn_mfma_f32_16x16x32_bf16(a3, b0, acc[3][0], 0, 0, 0);
    acc[3][1] = __builtin_amdgcn_mfma_f32_16x16x32_bf16(a3, b1, acc[3][1], 0, 0, 0);
  }

  // plane softmax + pool scale
  float amax = -3.402823466e38f;
#pragma unroll
  for (int mi = 0; mi < 4; ++mi)
#pragma unroll
    for (int ni = 0; ni < 2; ++ni)
#pragma unroll
      for (int j = 0; j < 4; ++j) amax = fmaxf(amax, acc[mi][ni][j]);
  amax = wave_max(amax);
  if (lane == 0) red[w] = amax;
  __syncthreads();
  float bmax = red[0];
#pragma unroll
  for (int w2 = 1; w2 < 8; ++w2) bmax = fmaxf(bmax, red[w2]);

  float es = 0.f;
#pragma unroll
  for (int mi = 0; mi < 4; ++mi)
#pragma unroll
    for (int ni = 0; ni < 2; ++ni)
#pragma unroll
      for (int j = 0; j < 4; ++j) {
        float e = __expf(acc[mi][ni][j] - bmax);
        acc[mi][ni][j] = e;
        es += e;
      }
  es = wave_sum(es);
  float ps = wave_sum(psum);
  if (lane == 0) { red[8 + w] = es; red[16 + w] = ps; }
  __syncthreads();
  float tsum = 0.f, tpool = 0.f;
#pragma unroll
  for (int w2 = 0; w2 < 8; ++w2) { tsum += red[8 + w2]; tpool += red[16 + w2]; }
  const float scale = (tpool * (1.f / 16384.f)) / tsum;

  unsigned short* __restrict__ yp = y + (size_t)bc * NPX;
#pragma unroll
  for (int mi = 0; mi < 4; ++mi)
#pragma unroll
    for (int ni = 0; ni < 2; ++ni) {
      const int col = wc * 32 + ni * 16 + r16;
#pragma unroll
      for (int j = 0; j < 4; ++j) {
        const int row = wr * 64 + mi * 16 + kg * 4 + j;
        yp[row * WDIM + col] = f2bf(acc[mi][ni][j] * scale);
      }
    }
}

// ---------------- Kernel S: s = w_sq . y via MFMA + stats + sT (bf16) -------
__global__ __launch_bounds__(256, 2)
void kS(const unsigned short* __restrict__ y, const float* __restrict__ w_sq,
        unsigned short* __restrict__ sT, float* __restrict__ partials) {
  __shared__ unsigned short yT[64][264];
  __shared__ float red[256];
  const int t = threadIdx.x;
  const int w = t >> 6, lane = t & 63;
  const int r16 = lane & 15, kg = lane >> 4;
  const int b = blockIdx.x >> 6;
  const int chunk = blockIdx.x & 63;
  const unsigned short* __restrict__ yb = y + (size_t)b * 256 * NPX;

  short8 aw[2][8];
#pragma unroll
  for (int mt = 0; mt < 2; ++mt)
#pragma unroll
    for (int ks = 0; ks < 8; ++ks) {
      const float* p = &w_sq[(mt * 16 + r16) * 256 + ks * 32 + kg * 8];
      float4 f0 = *(const float4*)p;
      float4 f1 = *(const float4*)(p + 4);
      short8 a;
      a[0] = f2bf(f0.x); a[1] = f2bf(f0.y); a[2] = f2bf(f0.z); a[3] = f2bf(f0.w);
      a[4] = f2bf(f1.x); a[5] = f2bf(f1.y); a[6] = f2bf(f1.z); a[7] = f2bf(f1.w);
      aw[mt][ks] = a;
    }

  float ssum[8], ssq[8];
#pragma unroll
  for (int i = 0; i < 8; ++i) { ssum[i] = 0.f; ssq[i] = 0.f; }

  for (int st = 0; st < 4; ++st) {
    const int p0 = chunk * 256 + st * 64;
#pragma unroll
    for (int it = 0; it < 8; ++it) {
      const int tid = it * 4 + w;
      const int cg = tid & 3, pg = tid >> 2;
      const int c = cg * 64 + lane;
      short8 v = *(const short8*)&yb[(size_t)c * NPX + p0 + pg * 8];
#pragma unroll
      for (int j = 0; j < 8; ++j) yT[pg * 8 + j][c] = (unsigned short)v[j];
    }
    __syncthreads();

    f32x4 acc[2][4];
#pragma unroll
    for (int mi = 0; mi < 2; ++mi)
#pragma unroll
      for (int ni = 0; ni < 4; ++ni) acc[mi][ni] = (f32x4){0.f, 0.f, 0.f, 0.f};

#pragma unroll
    for (int ks = 0; ks < 8; ++ks) {
#pragma unroll
      for (int ni = 0; ni < 4; ++ni) {
        short8 bv = *(const short8*)&yT[ni * 16 + r16][ks * 32 + kg * 8];
        acc[0][ni] = __builtin_amdgcn_mfma_f32_16x16x32_bf16(aw[0][ks], bv, acc[0][ni], 0, 0, 0);
        acc[1][ni] = __builtin_amdgcn_mfma_f32_16x16x32_bf16(aw[1][ks], bv, acc[1][ni], 0, 0, 0);
      }
    }

#pragma unroll
    for (int mi = 0; mi < 2; ++mi)
#pragma unroll
      for (int ni = 0; ni < 4; ++ni) {
        const int px = p0 + ni * 16 + r16;
        ushort4 pk;
#pragma unroll
        for (int j = 0; j < 4; ++j) {
          float v = acc[mi][ni][j];
          ssum[mi * 4 + j] += v;
          ssq[mi * 4 + j] += v * v;
          ((unsigned short*)&pk)[j] = f2bf(v);
        }
        *(ushort4*)&sT[((size_t)b * NPX + px) * 32 + mi * 16 + kg * 4] = pk;
      }
    __syncthreads();
  }

#pragma unroll
  for (int i = 0; i < 8; ++i) {
    float sm = ssum[i], sq = ssq[i];
#pragma unroll
    for (int m = 8; m >= 1; m >>= 1) {
      sm += __shfl_xor(sm, m);
      sq += __shfl_xor(sq, m);
    }
    if (r16 == 0) {
      const int d = (i >> 2) * 16 + kg * 4 + (i & 3);
      red[w * 64 + d] = sm;
      red[w * 64 + 32 + d] = sq;
    }
  }
  __syncthreads();
  if (t < 64) {
    float tot = red[t] + red[64 + t] + red[128 + t] + red[192 + t];
    partials[(size_t)blockIdx.x * 64 + t] = tot;
  }
}

// ---------------- Kernel R: partials -> mu, rs ------------------------------
__global__ void kR(const float* __restrict__ partials, float* __restrict__ mu_rs) {
  const int b = blockIdx.x, d = threadIdx.x;
  float sm = 0.f, sq = 0.f;
  for (int ch = 0; ch < 64; ++ch) {
    const float* pp = &partials[(size_t)(b * 64 + ch) * 64];
    sm += pp[d];
    sq += pp[32 + d];
  }
  float m = sm * (1.f / 16384.f);
  float v = sq * (1.f / 16384.f) - m * m;
  mu_rs[b * 64 + d] = m;
  mu_rs[b * 64 + 32 + d] = rsqrtf(v + 1e-5f);
}

// ---------------- Kernel O: out = w_ex . relu((s-mu)*rs) + b_ex (MFMA) ------
__global__ __launch_bounds__(256, 3)
void kO(const unsigned short* __restrict__ sT, const float* __restrict__ mu_rs,
        const float* __restrict__ w_ex, const float* __restrict__ b_ex,
        float* __restrict__ out) {
  const int t = threadIdx.x;
  const int w = t >> 6, lane = t & 63;
  const int r16 = lane & 15, kg = lane >> 4;
  const int b = blockIdx.x >> 8;
  const int p0 = (blockIdx.x & 255) * 64;
  const int c0 = w * 64;

  short8 aw[4];
#pragma unroll
  for (int mt = 0; mt < 4; ++mt) {
    const int c = c0 + mt * 16 + r16;
    const float* p = &w_ex[c * 32 + kg * 8];
    float4 f0 = *(const float4*)p;
    float4 f1 = *(const float4*)(p + 4);
    short8 a;
    a[0] = f2bf(f0.x); a[1] = f2bf(f0.y); a[2] = f2bf(f0.z); a[3] = f2bf(f0.w);
    a[4] = f2bf(f1.x); a[5] = f2bf(f1.y); a[6] = f2bf(f1.z); a[7] = f2bf(f1.w);
    aw[mt] = a;
  }

  float m8[8], r8[8];
  {
    const float* mp = &mu_rs[b * 64 + kg * 8];
    const float* rp = &mu_rs[b * 64 + 32 + kg * 8];
#pragma unroll
    for (int q = 0; q < 8; ++q) { m8[q] = mp[q]; r8[q] = rp[q]; }
  }

  f32x4 acc[4][4];
#pragma unroll
  for (int mt = 0; mt < 4; ++mt)
#pragma unroll
    for (int ni = 0; ni < 4; ++ni) acc[mt][ni] = (f32x4){0.f, 0.f, 0.f, 0.f};

#pragma unroll
  for (int ni = 0; ni < 4; ++ni) {
    const int px = p0 + ni * 16 + r16;
    short8 sv = *(const short8*)&sT[((size_t)b * NPX + px) * 32 + kg * 8];
    short8 hb;
#pragma unroll
    for (int q = 0; q < 8; ++q) {
      float f = bf2f((unsigned short)sv[q]);
      float h = fmaxf((f - m8[q]) * r8[q], 0.f);
      hb[q] = f2bf(h);
    }
#pragma unroll
    for (int mt = 0; mt < 4; ++mt)
      acc[mt][ni] = __builtin_amdgcn_mfma_f32_16x16x32_bf16(aw[mt], hb, acc[mt][ni], 0, 0, 0);
  }

  float* __restrict__ ob = out + (size_t)b * 256 * NPX;
#pragma unroll
  for (int mt = 0; mt < 4; ++mt) {
#pragma unroll
    for (int j = 0; j < 4; ++j) {
      const int c = c0 + mt * 16 + kg * 4 + j;
      const float bv = b_ex[c];
#pragma unroll
      for (int ni = 0; ni < 4; ++ni) {
        const int px = p0 + ni * 16 + r16;
        ob[(size_t)c * NPX + px] = acc[mt][ni][j] + bv;
      }
    }
  }
}

extern "C" void kernel_launch(void* const* d_in, const int* in_sizes, int n_in,
                              void* d_out, int out_size, void* d_ws, size_t ws_size,
                              hipStream_t stream) {
  (void)in_sizes; (void)n_in; (void)out_size; (void)ws_size;
  const float* x    = (const float*)d_in[0];
  const float* wq   = (const float*)d_in[1];
  const float* bq   = (const float*)d_in[2];
  const float* wk   = (const float*)d_in[3];
  const float* bk   = (const float*)d_in[4];
  const float* w_sq = (const float*)d_in[5];
  // d_in[6] = b_sq: unused — per-channel bias before InstanceNorm cancels
  const float* w_ex = (const float*)d_in[7];
  const float* b_ex = (const float*)d_in[8];
  float* out = (float*)d_out;

  unsigned short* sT = (unsigned short*)d_ws;
  float* partials = (float*)((char*)d_ws + (size_t)8 * NPX * 32 * 2);
  float* mu_rs = partials + (size_t)512 * 64;

  unsigned short* ybf = (unsigned short*)d_out;

  hipFuncSetAttribute((const void*)kA, hipFuncAttributeMaxDynamicSharedMemorySize,
                      LDS_A_BYTES);

  kA<<<2048, 512, LDS_A_BYTES, stream>>>(x, wq, bq, wk, bk, ybf);
  kS<<<512, 256, 0, stream>>>(ybf, w_sq, sT, partials);
  kR<<<8, 32, 0, stream>>>(partials, mu_rs);
  kO<<<2048, 256, 0, stream>>>(sT, mu_rs, w_ex, b_ex, out);
}